// Round 3
// baseline (430.153 us; speedup 1.0000x reference)
//
#include <hip/hip_runtime.h>
#include <math.h>

#define G_TOT   16380
#define N_NODES 10242
#define LATN    91
#define LONN    180
#define CH      64
#define NBATCH  4
#define KNN     8

// workspace layout (bytes)
#define WS_W_OFF 0                       // float  [G_TOT][8]  weights
#define WS_I_OFF (G_TOT * KNN * 4)       // int    [G_TOT][8]  indices   (524160)
#define WS_T_OFF (2 * G_TOT * KNN * 4)   // float4 [N_NODES]   node table (1048320)

// ---------------------------------------------------------------------------
// kernel 0: build node table {x, y, z, m2} with m2 replicating np f32:
//   m2 = round(round(x*x) + round(y*y)) + round(z*z)   (no FMA!)
// ---------------------------------------------------------------------------
__global__ __launch_bounds__(256) void build_table(const float* __restrict__ mv,
                                                   float4* __restrict__ tbl) {
    int i = blockIdx.x * 256 + threadIdx.x;
    if (i < N_NODES) {
        float x = mv[3 * i + 0], y = mv[3 * i + 1], z = mv[3 * i + 2];
        float m2 = __fadd_rn(__fadd_rn(__fmul_rn(x, x), __fmul_rn(y, y)),
                             __fmul_rn(z, z));
        tbl[i] = make_float4(x, y, z, m2);
    }
}

// ---------------------------------------------------------------------------
// kernel 1: top-8 per grid point, ranking EXACTLY as the f32 numpy reference:
//   d2  = fsub(fadd(g2, m2), fma(2gz*mz, fma(2gy*my, round(2gx*mx))))
//   key = (bits(sqrtf(max(d2,1e-12))) << 32) | node_idx   (lowest-idx ties)
//   block = 512 thr = 8 waves; lane = grid point, wave = node slice (scalar
//   node loads).
// ---------------------------------------------------------------------------
__global__ __launch_bounds__(512) void knn_weights(const float* __restrict__ lat,
                                                   const float* __restrict__ lon,
                                                   const float4* __restrict__ tbl,
                                                   float* __restrict__ wts,
                                                   int* __restrict__ nidx) {
    __shared__ unsigned gpw[64];                      // 8th-best dist bits per gp
    __shared__ unsigned long long lkeys[8][64][KNN];  // 32 KiB

    const int t  = threadIdx.x;
    const int gl = t & 63;                                   // lane  = local grid point
    const int w  = __builtin_amdgcn_readfirstlane(t >> 6);   // wave  = node slice 0..7
    const int gp = blockIdx.x * 64 + gl;
    const int gpc = gp < G_TOT ? gp : G_TOT - 1;

    if (t < 64) gpw[t] = 0x7f800000u;  // +inf
    __syncthreads();

    // grid coords: f64 trig rounded to f32 (= correctly-rounded f32 cos/sin),
    // then f32 products — replicating np f32 grid_pos construction.
    const int li = gpc / LONN, lj = gpc - li * LONN;
    const double dla = (double)lat[li], dlo = (double)lon[lj];
    const float cl = (float)cos(dla), sl = (float)sin(dla);
    const float co = (float)cos(dlo), so = (float)sin(dlo);
    const float gx = __fmul_rn(cl, co);
    const float gy = __fmul_rn(cl, so);
    const float gz = sl;
    // g2 np-style (no FMA)
    const float g2 = __fadd_rn(__fadd_rn(__fmul_rn(gx, gx), __fmul_rn(gy, gy)),
                               __fmul_rn(gz, gz));
    // A row of (2.0*grid_pos) — exact doubling, as in (2.0*grid_pos) @ mv.T
    const float ax = 2.0f * gx, ay = 2.0f * gy, az = 2.0f * gz;

    // local top-8 as packed keys: (dist_f32_bits << 32) | idx
    unsigned long long kk[KNN];
#pragma unroll
    for (int q = 0; q < KNN; ++q) kk[q] = ~0ull;

    for (int j0 = w; j0 < N_NODES; j0 += 8 * 16) {
        // d2 prune bound from shared 8th-best dist: d2 <= bd^2 (+margin)
        float bd  = __uint_as_float(gpw[gl]);
        float bd2 = __fmaf_rn(bd, bd, 1e-7f);  // inf stays inf while not full
#pragma unroll
        for (int u = 0; u < 16; ++u) {
            int j = j0 + u * 8;
            if (j >= N_NODES) break;
            float4 nd = tbl[j];  // wave-uniform -> s_load_dwordx4
            // sgemm K=3, beta=0, FMA, ascending k:
            float dot2 = __fmaf_rn(az, nd.z,
                          __fmaf_rn(ay, nd.y, __fmul_rn(ax, nd.x)));
            float d2 = __fsub_rn(__fadd_rn(g2, nd.w), dot2);
            if (d2 <= bd2) {
                float sq = sqrtf(fmaxf(d2, 1e-12f));  // np: sqrt(maximum(d2,1e-12))
                unsigned long long key =
                    ((unsigned long long)__float_as_uint(sq) << 32) |
                    (unsigned long long)(unsigned)j;
                if (key < kk[KNN - 1]) {
                    kk[KNN - 1] = key;
#pragma unroll
                    for (int q = KNN - 1; q > 0; --q) {  // single-bubble resort
                        unsigned long long a = kk[q - 1], c = kk[q];
                        bool m = c < a;
                        kk[q - 1] = m ? c : a;
                        kk[q]     = m ? a : c;
                    }
                    unsigned hb = (unsigned)(kk[KNN - 1] >> 32);  // 0xFFFFFFFF if !full
                    atomicMin(&gpw[gl], hb);
                }
            }
        }
    }

#pragma unroll
    for (int q = 0; q < KNN; ++q) lkeys[w][gl][q] = kk[q];
    __syncthreads();

    // merge 8 sorted lists per grid point; thread t<64 handles gp t
    if (t < 64) {
        int g = blockIdx.x * 64 + t;
        if (g < G_TOT) {
            int pos[8];
#pragma unroll
            for (int s = 0; s < 8; ++s) pos[s] = 0;
            float dist[KNN];
            int   idxs[KNN];
            for (int r = 0; r < KNN; ++r) {
                unsigned long long best = ~0ull;
                int bs = 0;
#pragma unroll
                for (int s = 0; s < 8; ++s) {
                    unsigned long long v = (pos[s] < KNN) ? lkeys[s][t][pos[s]] : ~0ull;
                    if (v < best) { best = v; bs = s; }
                }
#pragma unroll
                for (int s = 0; s < 8; ++s) pos[s] += (s == bs) ? 1 : 0;
                dist[r] = __uint_as_float((unsigned)(best >> 32));
                idxs[r] = (int)(best & 0xFFFFFFFFULL);
            }
            float e[KNN];
            float ssum = 0.f;
#pragma unroll
            for (int r = 0; r < KNN; ++r) {  // softmax(-dist), max = -dist[0]
                e[r] = expf(dist[0] - dist[r]);
                ssum += e[r];
            }
#pragma unroll
            for (int r = 0; r < KNN; ++r) {
                wts[g * KNN + r]  = e[r] / ssum;
                nidx[g * KNN + r] = idxs[r];
            }
        }
    }
}

// ---------------------------------------------------------------------------
// kernel 2: gather + weighted sum -> h, then y = W h + b, transposed store
//   block = 256 thr, handles (batch b, 64-grid-point tile)
//   phase 1: lane = channel (coalesced mesh gather); phase 2: lane = grid point
//   (coalesced output store). LDS h tile padded to stride 65 (conflict-free).
// ---------------------------------------------------------------------------
__global__ __launch_bounds__(256) void interp_apply(const float* __restrict__ mesh,
                                                    const float* __restrict__ Wm,
                                                    const float* __restrict__ bias,
                                                    const float* __restrict__ wts,
                                                    const int* __restrict__ nidx,
                                                    float* __restrict__ out) {
    __shared__ float hlds[64 * 65];
    const int tile = blockIdx.x & 255;
    const int b    = blockIdx.x >> 8;
    const int t  = threadIdx.x;
    const int wv = __builtin_amdgcn_readfirstlane(t >> 6);
    const int ln = t & 63;
    const int g0 = tile * 64;

#pragma unroll 1
    for (int gs = 0; gs < 16; ++gs) {
        int gl = wv * 16 + gs;
        int gc = min(g0 + gl, G_TOT - 1);
        float acc = 0.f;
#pragma unroll
        for (int k = 0; k < KNN; ++k) {
            int   id = nidx[gc * KNN + k];   // wave-uniform -> scalar load
            float wk = wts[gc * KNN + k];
            acc = fmaf(wk, mesh[((size_t)b * N_NODES + id) * CH + ln], acc);
        }
        hlds[gl * 65 + ln] = acc;
    }
    __syncthreads();

    float h[CH];
#pragma unroll
    for (int c = 0; c < CH; ++c) h[c] = hlds[ln * 65 + c];
    int g = g0 + ln;
    if (g < G_TOT) {
#pragma unroll 1
        for (int cs = 0; cs < 16; ++cs) {
            int cp = wv * 16 + cs;
            float y = bias[cp];
#pragma unroll
            for (int c = 0; c < CH; ++c) y = fmaf(Wm[cp * CH + c], h[c], y);  // W uniform -> s_load
            out[((size_t)b * CH + cp) * G_TOT + g] = y;
        }
    }
}

// ---------------------------------------------------------------------------
extern "C" void kernel_launch(void* const* d_in, const int* in_sizes, int n_in,
                              void* d_out, int out_size, void* d_ws, size_t ws_size,
                              hipStream_t stream) {
    const float* mesh = (const float*)d_in[0];  // [4][10242][64]
    const float* mv   = (const float*)d_in[1];  // [10242][3]
    const float* lat  = (const float*)d_in[2];  // [91]
    const float* lon  = (const float*)d_in[3];  // [180]
    const float* Wm   = (const float*)d_in[4];  // [64][64]
    const float* bias = (const float*)d_in[5];  // [64]
    float* out = (float*)d_out;                 // [4][64][91][180]

    float*  wts = (float*)((char*)d_ws + WS_W_OFF);
    int*    nid = (int*)((char*)d_ws + WS_I_OFF);
    float4* tbl = (float4*)((char*)d_ws + WS_T_OFF);

    hipLaunchKernelGGL(build_table, dim3((N_NODES + 255) / 256), dim3(256), 0, stream,
                       mv, tbl);
    hipLaunchKernelGGL(knn_weights, dim3((G_TOT + 63) / 64), dim3(512), 0, stream,
                       lat, lon, tbl, wts, nid);
    hipLaunchKernelGGL(interp_apply, dim3(NBATCH * 256), dim3(256), 0, stream,
                       mesh, Wm, bias, wts, nid, out);
}

// Round 4
// 270.107 us; speedup vs baseline: 1.5925x; 1.5925x over previous
//
#include <hip/hip_runtime.h>
#include <math.h>

#define G_TOT   16380
#define N_NODES 10242
#define LATN    91
#define LONN    180
#define CH      64
#define NBATCH  4
#define KNN     8

#define CHUNK   1296                 // per-wave contiguous node chunk (81*16)
#define N_PAD   (8 * CHUNK)          // 10368: padded with far sentinels

// workspace layout (bytes)
#define WS_W_OFF 0                       // float  [G_TOT][8]  weights
#define WS_I_OFF (G_TOT * KNN * 4)       // int    [G_TOT][8]  indices
#define WS_T_OFF (2 * G_TOT * KNN * 4)   // float4 [N_PAD]     node table

// ---------------------------------------------------------------------------
// kernel 0: build node table {x, y, z, m2} with m2 replicating np f32 (no FMA).
// Padding [N_NODES, N_PAD): sentinel (2,0,0,4) — distance >= 1.0 from any
// on-sphere point, so it can never enter a true top-8 (real 8th-NN << 1.0);
// lets the main loop drop all bounds checks.
// ---------------------------------------------------------------------------
__global__ __launch_bounds__(256) void build_table(const float* __restrict__ mv,
                                                   float4* __restrict__ tbl) {
    int i = blockIdx.x * 256 + threadIdx.x;
    if (i < N_PAD) {
        if (i < N_NODES) {
            float x = mv[3 * i + 0], y = mv[3 * i + 1], z = mv[3 * i + 2];
            float m2 = __fadd_rn(__fadd_rn(__fmul_rn(x, x), __fmul_rn(y, y)),
                                 __fmul_rn(z, z));
            tbl[i] = make_float4(x, y, z, m2);
        } else {
            tbl[i] = make_float4(2.0f, 0.0f, 0.0f, 4.0f);
        }
    }
}

// ---------------------------------------------------------------------------
// kernel 1: top-8 per grid point, ranking EXACTLY as the f32 numpy reference:
//   d2  = fsub(fadd(g2, m2), fma(az,mz, fma(ay,my, mul(ax,mx))))   (a = 2*g)
//   key = (bits(sqrtf(max(d2,1e-12))) << 32) | node_idx   (lowest-idx ties)
// block = 512 thr = 8 waves; lane = grid point, wave = CONTIGUOUS node chunk.
// 16 nodes are staged into registers per inner block: 16 independent
// wave-uniform loads -> wide scalar loads, latency amortized 16x (R3 was
// 300 cyc/iter: one dependent stride-128B s_load per candidate).
// ---------------------------------------------------------------------------
__global__ __launch_bounds__(512) void knn_weights(const float* __restrict__ lat,
                                                   const float* __restrict__ lon,
                                                   const float4* __restrict__ tbl,
                                                   float* __restrict__ wts,
                                                   int* __restrict__ nidx) {
    __shared__ unsigned gpw[64];                      // 8th-best dist bits per gp
    __shared__ unsigned long long lkeys[8][64][KNN];  // 32 KiB

    const int t  = threadIdx.x;
    const int gl = t & 63;                                   // lane  = local grid point
    const int w  = __builtin_amdgcn_readfirstlane(t >> 6);   // wave  = node chunk 0..7
    const int gp = blockIdx.x * 64 + gl;
    const int gpc = gp < G_TOT ? gp : G_TOT - 1;

    if (t < 64) gpw[t] = 0x7f800000u;  // +inf
    __syncthreads();

    // grid coords: f64 trig rounded to f32 (= correctly-rounded f32 cos/sin),
    // then f32 products — replicating np f32 grid_pos construction.
    const int li = gpc / LONN, lj = gpc - li * LONN;
    const double dla = (double)lat[li], dlo = (double)lon[lj];
    const float cl = (float)cos(dla), sl = (float)sin(dla);
    const float co = (float)cos(dlo), so = (float)sin(dlo);
    const float gx = __fmul_rn(cl, co);
    const float gy = __fmul_rn(cl, so);
    const float gz = sl;
    const float g2 = __fadd_rn(__fadd_rn(__fmul_rn(gx, gx), __fmul_rn(gy, gy)),
                               __fmul_rn(gz, gz));
    const float ax = 2.0f * gx, ay = 2.0f * gy, az = 2.0f * gz;  // (2*grid_pos) row

    unsigned long long kk[KNN];
#pragma unroll
    for (int q = 0; q < KNN; ++q) kk[q] = ~0ull;

    const int jbeg = w * CHUNK;
    for (int j0 = jbeg; j0 < jbeg + CHUNK; j0 += 16) {
        // stage 16 nodes: independent wave-uniform loads -> batched wide loads
        float4 nd[16];
#pragma unroll
        for (int u = 0; u < 16; ++u) nd[u] = tbl[j0 + u];

        float bd  = __uint_as_float(gpw[gl]);     // shared 8th-best dist (stale ok)
        float bd2 = __fmaf_rn(bd, bd, 1e-7f);     // margin >> f32 rounding slop
#pragma unroll
        for (int u = 0; u < 16; ++u) {
            // sgemm K=3, beta=0, FMA, ascending k (np f32 replication):
            float dot2 = __fmaf_rn(az, nd[u].z,
                          __fmaf_rn(ay, nd[u].y, __fmul_rn(ax, nd[u].x)));
            float d2 = __fsub_rn(__fadd_rn(g2, nd[u].w), dot2);
            if (d2 <= bd2) {
                float sq = sqrtf(fmaxf(d2, 1e-12f));  // np: sqrt(maximum(d2,1e-12))
                unsigned long long key =
                    ((unsigned long long)__float_as_uint(sq) << 32) |
                    (unsigned long long)(unsigned)(j0 + u);
                if (key < kk[KNN - 1]) {
                    kk[KNN - 1] = key;
#pragma unroll
                    for (int q = KNN - 1; q > 0; --q) {  // single-bubble resort
                        unsigned long long a = kk[q - 1], c = kk[q];
                        bool m = c < a;
                        kk[q - 1] = m ? c : a;
                        kk[q]     = m ? a : c;
                    }
                    unsigned hb = (unsigned)(kk[KNN - 1] >> 32);  // 0xFFFFFFFF if !full
                    atomicMin(&gpw[gl], hb);
                }
            }
        }
    }

#pragma unroll
    for (int q = 0; q < KNN; ++q) lkeys[w][gl][q] = kk[q];
    __syncthreads();

    // merge 8 sorted lists per grid point; thread t<64 handles gp t
    if (t < 64) {
        int g = blockIdx.x * 64 + t;
        if (g < G_TOT) {
            int pos[8];
#pragma unroll
            for (int s = 0; s < 8; ++s) pos[s] = 0;
            float dist[KNN];
            int   idxs[KNN];
            for (int r = 0; r < KNN; ++r) {
                unsigned long long best = ~0ull;
                int bs = 0;
#pragma unroll
                for (int s = 0; s < 8; ++s) {
                    unsigned long long v = (pos[s] < KNN) ? lkeys[s][t][pos[s]] : ~0ull;
                    if (v < best) { best = v; bs = s; }
                }
#pragma unroll
                for (int s = 0; s < 8; ++s) pos[s] += (s == bs) ? 1 : 0;
                dist[r] = __uint_as_float((unsigned)(best >> 32));
                idxs[r] = (int)(best & 0xFFFFFFFFULL);
            }
            float e[KNN];
            float ssum = 0.f;
#pragma unroll
            for (int r = 0; r < KNN; ++r) {  // softmax(-dist), max = -dist[0]
                e[r] = expf(dist[0] - dist[r]);
                ssum += e[r];
            }
#pragma unroll
            for (int r = 0; r < KNN; ++r) {
                wts[g * KNN + r]  = e[r] / ssum;
                nidx[g * KNN + r] = idxs[r];
            }
        }
    }
}

// ---------------------------------------------------------------------------
// kernel 2: gather + weighted sum -> h, then y = W h + b, transposed store
//   block = 256 thr, handles (batch b, 64-grid-point tile)
//   phase 1: lane = channel (coalesced mesh gather); phase 2: lane = grid point
//   (coalesced output store). LDS h tile padded to stride 65 (conflict-free).
// ---------------------------------------------------------------------------
__global__ __launch_bounds__(256) void interp_apply(const float* __restrict__ mesh,
                                                    const float* __restrict__ Wm,
                                                    const float* __restrict__ bias,
                                                    const float* __restrict__ wts,
                                                    const int* __restrict__ nidx,
                                                    float* __restrict__ out) {
    __shared__ float hlds[64 * 65];
    const int tile = blockIdx.x & 255;
    const int b    = blockIdx.x >> 8;
    const int t  = threadIdx.x;
    const int wv = __builtin_amdgcn_readfirstlane(t >> 6);
    const int ln = t & 63;
    const int g0 = tile * 64;

#pragma unroll 1
    for (int gs = 0; gs < 16; ++gs) {
        int gl = wv * 16 + gs;
        int gc = min(g0 + gl, G_TOT - 1);
        float acc = 0.f;
#pragma unroll
        for (int k = 0; k < KNN; ++k) {
            int   id = nidx[gc * KNN + k];   // wave-uniform -> scalar load
            float wk = wts[gc * KNN + k];
            acc = fmaf(wk, mesh[((size_t)b * N_NODES + id) * CH + ln], acc);
        }
        hlds[gl * 65 + ln] = acc;
    }
    __syncthreads();

    float h[CH];
#pragma unroll
    for (int c = 0; c < CH; ++c) h[c] = hlds[ln * 65 + c];
    int g = g0 + ln;
    if (g < G_TOT) {
#pragma unroll 1
        for (int cs = 0; cs < 16; ++cs) {
            int cp = wv * 16 + cs;
            float y = bias[cp];
#pragma unroll
            for (int c = 0; c < CH; ++c) y = fmaf(Wm[cp * CH + c], h[c], y);  // W uniform -> s_load
            out[((size_t)b * CH + cp) * G_TOT + g] = y;
        }
    }
}

// ---------------------------------------------------------------------------
extern "C" void kernel_launch(void* const* d_in, const int* in_sizes, int n_in,
                              void* d_out, int out_size, void* d_ws, size_t ws_size,
                              hipStream_t stream) {
    const float* mesh = (const float*)d_in[0];  // [4][10242][64]
    const float* mv   = (const float*)d_in[1];  // [10242][3]
    const float* lat  = (const float*)d_in[2];  // [91]
    const float* lon  = (const float*)d_in[3];  // [180]
    const float* Wm   = (const float*)d_in[4];  // [64][64]
    const float* bias = (const float*)d_in[5];  // [64]
    float* out = (float*)d_out;                 // [4][64][91][180]

    float*  wts = (float*)((char*)d_ws + WS_W_OFF);
    int*    nid = (int*)((char*)d_ws + WS_I_OFF);
    float4* tbl = (float4*)((char*)d_ws + WS_T_OFF);

    hipLaunchKernelGGL(build_table, dim3((N_PAD + 255) / 256), dim3(256), 0, stream,
                       mv, tbl);
    hipLaunchKernelGGL(knn_weights, dim3((G_TOT + 63) / 64), dim3(512), 0, stream,
                       lat, lon, tbl, wts, nid);
    hipLaunchKernelGGL(interp_apply, dim3(NBATCH * 256), dim3(256), 0, stream,
                       mesh, Wm, bias, wts, nid, out);
}

// Round 5
// 212.272 us; speedup vs baseline: 2.0264x; 1.2725x over previous
//
#include <hip/hip_runtime.h>
#include <math.h>

#define G_TOT   16380
#define N_NODES 10242
#define LATN    91
#define LONN    180
#define CH      64
#define NBATCH  4
#define KNN     8

#define NWAVE   16
#define CHUNK   656                  // 41*16 nodes per wave
#define N_PAD   (NWAVE * CHUNK)      // 10496: padded with far sentinels

// constant prune bound: chord^2 = 0.0144 (r=0.12). E[nodes inside] = 36.9;
// P(<8 inside) ~ 2e-9 per gp — and a brute-force fallback covers even that.
#define R2BOUND 0.0144f

// workspace layout (bytes)
#define WS_W_OFF 0                       // float  [G_TOT][8]  weights
#define WS_I_OFF (G_TOT * KNN * 4)       // int    [G_TOT][8]  indices
#define WS_T_OFF (2 * G_TOT * KNN * 4)   // float4 [N_PAD]     node table

// ---------------------------------------------------------------------------
// kernel 0: build node table {x, y, z, m2} with m2 replicating np f32 (no FMA).
// Padding [N_NODES, N_PAD): sentinel (2,0,0,4) — d2 >= 1.0 from any on-sphere
// point, never passes R2BOUND.
// ---------------------------------------------------------------------------
__global__ __launch_bounds__(256) void build_table(const float* __restrict__ mv,
                                                   float4* __restrict__ tbl) {
    int i = blockIdx.x * 256 + threadIdx.x;
    if (i < N_PAD) {
        if (i < N_NODES) {
            float x = mv[3 * i + 0], y = mv[3 * i + 1], z = mv[3 * i + 2];
            float m2 = __fadd_rn(__fadd_rn(__fmul_rn(x, x), __fmul_rn(y, y)),
                                 __fmul_rn(z, z));
            tbl[i] = make_float4(x, y, z, m2);
        } else {
            tbl[i] = make_float4(2.0f, 0.0f, 0.0f, 4.0f);
        }
    }
}

// ---------------------------------------------------------------------------
// kernel 1: top-8 per grid point, ranking EXACTLY as the f32 numpy reference:
//   d2  = fsub(fadd(g2, m2), fma(az,mz, fma(ay,my, mul(ax,mx))))   (a = 2*g)
//   rank by bits(sqrtf(max(d2,1e-12))), lowest-index tie-break.
// block = 1024 thr = 16 waves (4/SIMD); lane = grid point, wave = contiguous
// 656-node chunk. Constant R2BOUND prune: no shared bound, no LDS atomics.
// ---------------------------------------------------------------------------
__global__ __launch_bounds__(1024) void knn_weights(const float* __restrict__ lat,
                                                    const float* __restrict__ lon,
                                                    const float4* __restrict__ tbl,
                                                    float* __restrict__ wts,
                                                    int* __restrict__ nidx) {
    __shared__ unsigned       skey[NWAVE][64][KNN];  // 32 KiB  sq-bits
    __shared__ unsigned short sidx[NWAVE][64][KNN];  // 16 KiB  local node offset

    const int t  = threadIdx.x;
    const int gl = t & 63;                                   // lane  = local grid point
    const int w  = __builtin_amdgcn_readfirstlane(t >> 6);   // wave  = node chunk 0..15
    const int gp = blockIdx.x * 64 + gl;
    const int gpc = gp < G_TOT ? gp : G_TOT - 1;

    // grid coords: f64 trig rounded to f32 (= correctly-rounded f32 cos/sin),
    // then f32 products — replicating np f32 grid_pos construction.
    const int li = gpc / LONN, lj = gpc - li * LONN;
    const double dla = (double)lat[li], dlo = (double)lon[lj];
    const float cl = (float)cos(dla), sl = (float)sin(dla);
    const float co = (float)cos(dlo), so = (float)sin(dlo);
    const float gx = __fmul_rn(cl, co);
    const float gy = __fmul_rn(cl, so);
    const float gz = sl;
    const float g2 = __fadd_rn(__fadd_rn(__fmul_rn(gx, gx), __fmul_rn(gy, gy)),
                               __fmul_rn(gz, gz));
    const float ax = 2.0f * gx, ay = 2.0f * gy, az = 2.0f * gz;  // (2*grid_pos) row

    unsigned long long kk[KNN];  // (sq_bits << 32) | global_idx
#pragma unroll
    for (int q = 0; q < KNN; ++q) kk[q] = ~0ull;

    const int jbeg = w * CHUNK;
    for (int j0 = jbeg; j0 < jbeg + CHUNK; j0 += 16) {
        float4 nd[16];
#pragma unroll
        for (int u = 0; u < 16; ++u) nd[u] = tbl[j0 + u];  // wave-uniform -> s_load
#pragma unroll
        for (int u = 0; u < 16; ++u) {
            // sgemm K=3, beta=0, FMA, ascending k (np f32 replication):
            float dot2 = __fmaf_rn(az, nd[u].z,
                          __fmaf_rn(ay, nd[u].y, __fmul_rn(ax, nd[u].x)));
            float d2 = __fsub_rn(__fadd_rn(g2, nd[u].w), dot2);
            if (d2 <= R2BOUND) {
                float sq = sqrtf(fmaxf(d2, 1e-12f));  // np: sqrt(maximum(d2,1e-12))
                unsigned long long key =
                    ((unsigned long long)__float_as_uint(sq) << 32) |
                    (unsigned long long)(unsigned)(j0 + u);
                if (key < kk[KNN - 1]) {
                    kk[KNN - 1] = key;
#pragma unroll
                    for (int q = KNN - 1; q > 0; --q) {  // single-bubble resort
                        unsigned long long a = kk[q - 1], c = kk[q];
                        bool m = c < a;
                        kk[q - 1] = m ? c : a;
                        kk[q]     = m ? a : c;
                    }
                }
            }
        }
    }

#pragma unroll
    for (int q = 0; q < KNN; ++q) {
        skey[w][gl][q] = (unsigned)(kk[q] >> 32);
        sidx[w][gl][q] = (unsigned short)((unsigned)kk[q] - (unsigned)jbeg);
    }
    __syncthreads();

    // merge 16 sorted lists per grid point; thread t<64 handles gp t.
    // ties: strict < picks lowest s = lowest global index (chunks ascending).
    if (t < 64) {
        int g = blockIdx.x * 64 + t;
        if (g < G_TOT) {
            int pos[NWAVE];
#pragma unroll
            for (int s = 0; s < NWAVE; ++s) pos[s] = 0;
            float dist[KNN];
            int   idxs[KNN];
            bool  bad = false;
            for (int r = 0; r < KNN; ++r) {
                unsigned bestk = 0xFFFFFFFFu;
                int bs = 0;
#pragma unroll
                for (int s = 0; s < NWAVE; ++s) {
                    unsigned v = (pos[s] < KNN) ? skey[s][t][pos[s]] : 0xFFFFFFFFu;
                    if (v < bestk) { bestk = v; bs = s; }
                }
                if (bestk == 0xFFFFFFFFu) bad = true;  // <8 inside bound (never)
                dist[r] = __uint_as_float(bestk);
                idxs[r] = bs * CHUNK + (int)sidx[bs][t][pos[bs]];
#pragma unroll
                for (int s = 0; s < NWAVE; ++s) pos[s] += (s == bs) ? 1 : 0;
            }
            if (bad) {
                // guaranteed-correct fallback: full brute-force for this gp
                int li2 = g / LONN, lj2 = g - li2 * LONN;
                double dla2 = (double)lat[li2], dlo2 = (double)lon[lj2];
                float cl2 = (float)cos(dla2), sl2 = (float)sin(dla2);
                float co2 = (float)cos(dlo2), so2 = (float)sin(dlo2);
                float hx = __fmul_rn(cl2, co2), hy = __fmul_rn(cl2, so2), hz = sl2;
                float h2 = __fadd_rn(__fadd_rn(__fmul_rn(hx, hx), __fmul_rn(hy, hy)),
                                     __fmul_rn(hz, hz));
                float bx = 2.0f * hx, by = 2.0f * hy, bz = 2.0f * hz;
                unsigned long long mm[KNN];
#pragma unroll
                for (int q = 0; q < KNN; ++q) mm[q] = ~0ull;
                for (int j = 0; j < N_NODES; ++j) {
                    float4 nd = tbl[j];
                    float dot2 = __fmaf_rn(bz, nd.z,
                                  __fmaf_rn(by, nd.y, __fmul_rn(bx, nd.x)));
                    float d2 = __fsub_rn(__fadd_rn(h2, nd.w), dot2);
                    float sq = sqrtf(fmaxf(d2, 1e-12f));
                    unsigned long long key =
                        ((unsigned long long)__float_as_uint(sq) << 32) |
                        (unsigned long long)(unsigned)j;
                    if (key < mm[KNN - 1]) {
                        mm[KNN - 1] = key;
#pragma unroll
                        for (int q = KNN - 1; q > 0; --q) {
                            unsigned long long a = mm[q - 1], c = mm[q];
                            bool m = c < a;
                            mm[q - 1] = m ? c : a;
                            mm[q]     = m ? a : c;
                        }
                    }
                }
#pragma unroll
                for (int r = 0; r < KNN; ++r) {
                    dist[r] = __uint_as_float((unsigned)(mm[r] >> 32));
                    idxs[r] = (int)(mm[r] & 0xFFFFFFFFULL);
                }
            }
            float e[KNN];
            float ssum = 0.f;
#pragma unroll
            for (int r = 0; r < KNN; ++r) {  // softmax(-dist), max = -dist[0]
                e[r] = expf(dist[0] - dist[r]);
                ssum += e[r];
            }
#pragma unroll
            for (int r = 0; r < KNN; ++r) {
                wts[g * KNN + r]  = e[r] / ssum;
                nidx[g * KNN + r] = idxs[r];
            }
        }
    }
}

// ---------------------------------------------------------------------------
// kernel 2: gather + weighted sum -> h, then y = W h + b, transposed store
//   (unchanged from R4 — kept fixed to attribute this round's delta to knn;
//   its counters will surface in top-5 once knn shrinks)
// ---------------------------------------------------------------------------
__global__ __launch_bounds__(256) void interp_apply(const float* __restrict__ mesh,
                                                    const float* __restrict__ Wm,
                                                    const float* __restrict__ bias,
                                                    const float* __restrict__ wts,
                                                    const int* __restrict__ nidx,
                                                    float* __restrict__ out) {
    __shared__ float hlds[64 * 65];
    const int tile = blockIdx.x & 255;
    const int b    = blockIdx.x >> 8;
    const int t  = threadIdx.x;
    const int wv = __builtin_amdgcn_readfirstlane(t >> 6);
    const int ln = t & 63;
    const int g0 = tile * 64;

#pragma unroll 1
    for (int gs = 0; gs < 16; ++gs) {
        int gl = wv * 16 + gs;
        int gc = min(g0 + gl, G_TOT - 1);
        float acc = 0.f;
#pragma unroll
        for (int k = 0; k < KNN; ++k) {
            int   id = nidx[gc * KNN + k];   // wave-uniform -> scalar load
            float wk = wts[gc * KNN + k];
            acc = fmaf(wk, mesh[((size_t)b * N_NODES + id) * CH + ln], acc);
        }
        hlds[gl * 65 + ln] = acc;
    }
    __syncthreads();

    float h[CH];
#pragma unroll
    for (int c = 0; c < CH; ++c) h[c] = hlds[ln * 65 + c];
    int g = g0 + ln;
    if (g < G_TOT) {
#pragma unroll 1
        for (int cs = 0; cs < 16; ++cs) {
            int cp = wv * 16 + cs;
            float y = bias[cp];
#pragma unroll
            for (int c = 0; c < CH; ++c) y = fmaf(Wm[cp * CH + c], h[c], y);  // W uniform -> s_load
            out[((size_t)b * CH + cp) * G_TOT + g] = y;
        }
    }
}

// ---------------------------------------------------------------------------
extern "C" void kernel_launch(void* const* d_in, const int* in_sizes, int n_in,
                              void* d_out, int out_size, void* d_ws, size_t ws_size,
                              hipStream_t stream) {
    const float* mesh = (const float*)d_in[0];  // [4][10242][64]
    const float* mv   = (const float*)d_in[1];  // [10242][3]
    const float* lat  = (const float*)d_in[2];  // [91]
    const float* lon  = (const float*)d_in[3];  // [180]
    const float* Wm   = (const float*)d_in[4];  // [64][64]
    const float* bias = (const float*)d_in[5];  // [64]
    float* out = (float*)d_out;                 // [4][64][91][180]

    float*  wts = (float*)((char*)d_ws + WS_W_OFF);
    int*    nid = (int*)((char*)d_ws + WS_I_OFF);
    float4* tbl = (float4*)((char*)d_ws + WS_T_OFF);

    hipLaunchKernelGGL(build_table, dim3((N_PAD + 255) / 256), dim3(256), 0, stream,
                       mv, tbl);
    hipLaunchKernelGGL(knn_weights, dim3((G_TOT + 63) / 64), dim3(1024), 0, stream,
                       lat, lon, tbl, wts, nid);
    hipLaunchKernelGGL(interp_apply, dim3(NBATCH * 256), dim3(256), 0, stream,
                       mesh, Wm, bias, wts, nid, out);
}

// Round 6
// 174.800 us; speedup vs baseline: 2.4608x; 1.2144x over previous
//
#include <hip/hip_runtime.h>
#include <math.h>

#define G_TOT   16380
#define N_NODES 10242
#define LATN    91
#define LONN    180
#define CH      64
#define NBATCH  4
#define KNN     8

#define NW      8                    // waves per knn block
#define N_PAD   (8 * 1312)           // 10496 sentinel-padded table (fallback chunks)
#define CAP     1472                 // LDS candidate capacity (expected ~250)
#define TLA     8
#define TLO     8
#define NTI     ((LATN + TLA - 1) / TLA)   // 12
#define NTJ     ((LONN + TLO - 1) / TLO)   // 23

// search radius: chord^2 = 0.0144 (r=0.12). E[nodes inside]=36.9;
// P(8th-NN beyond r) ~ 2e-9/gp; brute-force fallback covers even that.
#define R2BOUND 0.0144f
#define RSNIP   0.121f               // r + slack for the patch filter

// workspace layout (bytes)
#define WS_W_OFF  0                            // float [G_TOT][8] weights
#define WS_I_OFF  (G_TOT * KNN * 4)            // int   [G_TOT][8] indices
#define WS_T_OFF  (2 * G_TOT * KNN * 4)        // float4[N_PAD]    node table
#define WS_SL_OFF (WS_T_OFF + N_PAD * 16)      // float [91]  sorted lat
#define WS_PL_OFF (WS_SL_OFF + LATN * 4)       // int   [91]  lat perm
#define WS_SO_OFF (WS_PL_OFF + LATN * 4)       // float [180] sorted lon
#define WS_PO_OFF (WS_SO_OFF + LONN * 4)       // int   [180] lon perm

// ---------------------------------------------------------------------------
// kernel 0: node table {x,y,z,m2}, m2 np-f32 style (no FMA). Sentinel pad
// (2,0,0,4): d2 >= 1 from any on-sphere point -> never accepted.
// ---------------------------------------------------------------------------
__global__ __launch_bounds__(256) void build_table(const float* __restrict__ mv,
                                                   float4* __restrict__ tbl) {
    int i = blockIdx.x * 256 + threadIdx.x;
    if (i < N_PAD) {
        if (i < N_NODES) {
            float x = mv[3 * i + 0], y = mv[3 * i + 1], z = mv[3 * i + 2];
            float m2 = __fadd_rn(__fadd_rn(__fmul_rn(x, x), __fmul_rn(y, y)),
                                 __fmul_rn(z, z));
            tbl[i] = make_float4(x, y, z, m2);
        } else {
            tbl[i] = make_float4(2.0f, 0.0f, 0.0f, 4.0f);
        }
    }
}

// ---------------------------------------------------------------------------
// kernel 0b: sort lat (91) and lon (180) with index perms. Odd-even
// transposition, n passes; pairs are disjoint per pass -> race-free.
// ---------------------------------------------------------------------------
__global__ __launch_bounds__(256) void sort_axes(const float* __restrict__ lat,
                                                 const float* __restrict__ lon,
                                                 float* __restrict__ slat,
                                                 int* __restrict__ plat,
                                                 float* __restrict__ slon,
                                                 int* __restrict__ plon) {
    __shared__ float v[LONN];
    __shared__ int   p[LONN];
    const int t = threadIdx.x;

    if (t < LATN) { v[t] = lat[t]; p[t] = t; }
    __syncthreads();
    for (int pass = 0; pass < LATN; ++pass) {
        int i = 2 * t + (pass & 1);
        if (i + 1 < LATN) {
            float a = v[i], b = v[i + 1];
            if (b < a) {
                v[i] = b; v[i + 1] = a;
                int pa = p[i]; p[i] = p[i + 1]; p[i + 1] = pa;
            }
        }
        __syncthreads();
    }
    if (t < LATN) { slat[t] = v[t]; plat[t] = p[t]; }
    __syncthreads();

    if (t < LONN) { v[t] = lon[t]; p[t] = t; }
    __syncthreads();
    for (int pass = 0; pass < LONN; ++pass) {
        int i = 2 * t + (pass & 1);
        if (i + 1 < LONN) {
            float a = v[i], b = v[i + 1];
            if (b < a) {
                v[i] = b; v[i + 1] = a;
                int pa = p[i]; p[i] = p[i + 1]; p[i + 1] = pa;
            }
        }
        __syncthreads();
    }
    if (t < LONN) { slon[t] = v[t]; plon[t] = p[t]; }
}

// ---------------------------------------------------------------------------
// kernel 1: spatial-patch KNN. One block per 8x8 sorted-rank patch (276).
// Phase 0: 64 gp coords (np-f32) + patch radius. Phase A: 512-thread
// coalesced compaction of nodes within R_patch+RSNIP of center into LDS.
// Phase B: 8 waves, lane = gp, scan compacted list with np-f32-exact key
//   d2  = fsub(fadd(g2,m2), fma(az,mz, fma(ay,my, mul(ax,mx))))
//   key = (bits(sqrtf(max(d2,1e-12))) << 32) | idx   (min-8 order-independent)
// Coverage: |n-g|<=0.12 => |n-c| <= R_patch+0.121 (triangle ineq + margin).
// Fallbacks: LDS overflow -> full-table scan; <8 found -> per-gp brute scan.
// ---------------------------------------------------------------------------
__global__ __launch_bounds__(512) void knn_weights(const float* __restrict__ slat,
                                                   const int* __restrict__ plat,
                                                   const float* __restrict__ slon,
                                                   const int* __restrict__ plon,
                                                   const float4* __restrict__ tbl,
                                                   float* __restrict__ wts,
                                                   int* __restrict__ nidx) {
    __shared__ float4             cand[CAP];            // 23552 B
    __shared__ int                cidx[CAP];            //  5888 B
    __shared__ unsigned long long lists[NW][64][KNN];   // 32768 B
    __shared__ float4             gpp[64];              //  1024 B
    __shared__ int                gorig[64];            //   256 B
    __shared__ int                cnt;
    __shared__ float              r2tot;

    const int t  = threadIdx.x;
    const int gl = t & 63;
    const int w  = __builtin_amdgcn_readfirstlane(t >> 6);
    const int ti = blockIdx.x / NTJ, tj = blockIdx.x % NTJ;

    // ---- phase 0: gp coords (np-f32 exact), output mapping, patch radius
    if (t < 64) {
        if (t == 0) cnt = 0;
        int ar = ti * TLA + (t >> 3), orr = tj * TLO + (t & 7);
        bool val = (ar < LATN) && (orr < LONN);
        int a = min(ar, LATN - 1), o = min(orr, LONN - 1);
        double dla = (double)slat[a], dlo = (double)slon[o];
        float cl = (float)cos(dla), sl = (float)sin(dla);
        float co = (float)cos(dlo), so = (float)sin(dlo);
        float gx = __fmul_rn(cl, co), gy = __fmul_rn(cl, so), gz = sl;
        float g2 = __fadd_rn(__fadd_rn(__fmul_rn(gx, gx), __fmul_rn(gy, gy)),
                             __fmul_rn(gz, gz));
        gpp[t]   = make_float4(gx, gy, gz, g2);
        gorig[t] = val ? (plat[a] * LONN + plon[o]) : -1;
    }
    __syncthreads();
    if (t < 64) {
        float4 c = gpp[27];                       // center: rank (3,3) gp
        float4 g = gpp[t];
        float dx = g.x - c.x, dy = g.y - c.y, dz = g.z - c.z;
        float d2c = dx * dx + dy * dy + dz * dz;
#pragma unroll
        for (int off = 32; off > 0; off >>= 1)
            d2c = fmaxf(d2c, __shfl_xor(d2c, off));
        if (t == 0) {
            float R = sqrtf(d2c) + RSNIP;
            r2tot = R * R + 1e-3f;                // f32-rounding headroom
        }
    }
    __syncthreads();

    // ---- phase A: coalesced compaction into LDS
    {
        float4 c = gpp[27];
        float r2t = r2tot;
        for (int j = t; j < N_NODES; j += 512) {
            float4 nd = tbl[j];
            float dx = nd.x - c.x, dy = nd.y - c.y, dz = nd.z - c.z;
            float d2c = dx * dx + dy * dy + dz * dz;
            if (d2c <= r2t) {
                int pos = atomicAdd(&cnt, 1);     // LDS atomic, wave-aggregated
                if (pos < CAP) { cand[pos] = nd; cidx[pos] = j; }
            }
        }
    }
    __syncthreads();
    const int  ncand = cnt;
    const bool ovf   = ncand > CAP;

    // ---- phase B: per-lane top-8 over compacted candidates
    const float4 gme = gpp[gl];
    const float  gx = gme.x, gy = gme.y, gz = gme.z, g2 = gme.w;
    const float  ax = 2.0f * gx, ay = 2.0f * gy, az = 2.0f * gz;

    unsigned long long kk[KNN];
#pragma unroll
    for (int q = 0; q < KNN; ++q) kk[q] = ~0ull;

    if (!ovf) {
        const int nn = ncand;
        for (int ci = w; ci < nn; ci += NW) {
            float4 nd = cand[ci];                 // wave-uniform ds_read (bcast)
            int    j  = cidx[ci];
            float dot2 = __fmaf_rn(az, nd.z,
                          __fmaf_rn(ay, nd.y, __fmul_rn(ax, nd.x)));
            float d2 = __fsub_rn(__fadd_rn(g2, nd.w), dot2);
            if (d2 <= R2BOUND) {
                float sq = sqrtf(fmaxf(d2, 1e-12f));
                unsigned long long key =
                    ((unsigned long long)__float_as_uint(sq) << 32) |
                    (unsigned long long)(unsigned)j;
                if (key < kk[KNN - 1]) {
                    kk[KNN - 1] = key;
#pragma unroll
                    for (int q = KNN - 1; q > 0; --q) {
                        unsigned long long a = kk[q - 1], c = kk[q];
                        bool m = c < a;
                        kk[q - 1] = m ? c : a;
                        kk[q]     = m ? a : c;
                    }
                }
            }
        }
    } else {
        // overflow fallback (never expected): full sentinel-padded table scan
        for (int j = w * 1312; j < (w + 1) * 1312; ++j) {
            float4 nd = tbl[j];
            float dot2 = __fmaf_rn(az, nd.z,
                          __fmaf_rn(ay, nd.y, __fmul_rn(ax, nd.x)));
            float d2 = __fsub_rn(__fadd_rn(g2, nd.w), dot2);
            if (d2 <= R2BOUND) {
                float sq = sqrtf(fmaxf(d2, 1e-12f));
                unsigned long long key =
                    ((unsigned long long)__float_as_uint(sq) << 32) |
                    (unsigned long long)(unsigned)j;
                if (key < kk[KNN - 1]) {
                    kk[KNN - 1] = key;
#pragma unroll
                    for (int q = KNN - 1; q > 0; --q) {
                        unsigned long long a = kk[q - 1], c = kk[q];
                        bool m = c < a;
                        kk[q - 1] = m ? c : a;
                        kk[q]     = m ? a : c;
                    }
                }
            }
        }
    }

#pragma unroll
    for (int q = 0; q < KNN; ++q) lists[w][gl][q] = kk[q];
    __syncthreads();

    // ---- merge 8 sorted lists per gp; softmax; scatter to original layout
    if (t < 64) {
        int g = gorig[t];
        if (g >= 0) {
            int pos[NW];
#pragma unroll
            for (int s = 0; s < NW; ++s) pos[s] = 0;
            float dist[KNN];
            int   idxs[KNN];
            bool  bad = false;
            for (int r = 0; r < KNN; ++r) {
                unsigned long long best = ~0ull;
                int bs = 0;
#pragma unroll
                for (int s = 0; s < NW; ++s) {
                    unsigned long long v = (pos[s] < KNN) ? lists[s][t][pos[s]] : ~0ull;
                    if (v < best) { best = v; bs = s; }
                }
                if (best == ~0ull) bad = true;
                dist[r] = __uint_as_float((unsigned)(best >> 32));
                idxs[r] = (int)(best & 0xFFFFFFFFULL);
#pragma unroll
                for (int s = 0; s < NW; ++s) pos[s] += (s == bs) ? 1 : 0;
            }
            if (bad) {
                // guaranteed-correct per-gp brute force (P ~ 4e-5 total)
                float4 gm = gpp[t];
                float bx = 2.0f * gm.x, by = 2.0f * gm.y, bz = 2.0f * gm.z;
                unsigned long long mm[KNN];
#pragma unroll
                for (int q = 0; q < KNN; ++q) mm[q] = ~0ull;
                for (int j = 0; j < N_NODES; ++j) {
                    float4 nd = tbl[j];
                    float dot2 = __fmaf_rn(bz, nd.z,
                                  __fmaf_rn(by, nd.y, __fmul_rn(bx, nd.x)));
                    float d2 = __fsub_rn(__fadd_rn(gm.w, nd.w), dot2);
                    float sq = sqrtf(fmaxf(d2, 1e-12f));
                    unsigned long long key =
                        ((unsigned long long)__float_as_uint(sq) << 32) |
                        (unsigned long long)(unsigned)j;
                    if (key < mm[KNN - 1]) {
                        mm[KNN - 1] = key;
#pragma unroll
                        for (int q = KNN - 1; q > 0; --q) {
                            unsigned long long a = mm[q - 1], c = mm[q];
                            bool m = c < a;
                            mm[q - 1] = m ? c : a;
                            mm[q]     = m ? a : c;
                        }
                    }
                }
#pragma unroll
                for (int r = 0; r < KNN; ++r) {
                    dist[r] = __uint_as_float((unsigned)(mm[r] >> 32));
                    idxs[r] = (int)(mm[r] & 0xFFFFFFFFULL);
                }
            }
            float e[KNN];
            float ssum = 0.f;
#pragma unroll
            for (int r = 0; r < KNN; ++r) {
                e[r] = expf(dist[0] - dist[r]);
                ssum += e[r];
            }
#pragma unroll
            for (int r = 0; r < KNN; ++r) {
                wts[g * KNN + r]  = e[r] / ssum;
                nidx[g * KNN + r] = idxs[r];
            }
        }
    }
}

// ---------------------------------------------------------------------------
// kernel 2: gather + weighted sum -> h, then y = W h + b, transposed store
//   (unchanged — will surface in top-5 now that knn shrinks)
// ---------------------------------------------------------------------------
__global__ __launch_bounds__(256) void interp_apply(const float* __restrict__ mesh,
                                                    const float* __restrict__ Wm,
                                                    const float* __restrict__ bias,
                                                    const float* __restrict__ wts,
                                                    const int* __restrict__ nidx,
                                                    float* __restrict__ out) {
    __shared__ float hlds[64 * 65];
    const int tile = blockIdx.x & 255;
    const int b    = blockIdx.x >> 8;
    const int t  = threadIdx.x;
    const int wv = __builtin_amdgcn_readfirstlane(t >> 6);
    const int ln = t & 63;
    const int g0 = tile * 64;

#pragma unroll 1
    for (int gs = 0; gs < 16; ++gs) {
        int gl = wv * 16 + gs;
        int gc = min(g0 + gl, G_TOT - 1);
        float acc = 0.f;
#pragma unroll
        for (int k = 0; k < KNN; ++k) {
            int   id = nidx[gc * KNN + k];
            float wk = wts[gc * KNN + k];
            acc = fmaf(wk, mesh[((size_t)b * N_NODES + id) * CH + ln], acc);
        }
        hlds[gl * 65 + ln] = acc;
    }
    __syncthreads();

    float h[CH];
#pragma unroll
    for (int c = 0; c < CH; ++c) h[c] = hlds[ln * 65 + c];
    int g = g0 + ln;
    if (g < G_TOT) {
#pragma unroll 1
        for (int cs = 0; cs < 16; ++cs) {
            int cp = wv * 16 + cs;
            float y = bias[cp];
#pragma unroll
            for (int c = 0; c < CH; ++c) y = fmaf(Wm[cp * CH + c], h[c], y);
            out[((size_t)b * CH + cp) * G_TOT + g] = y;
        }
    }
}

// ---------------------------------------------------------------------------
extern "C" void kernel_launch(void* const* d_in, const int* in_sizes, int n_in,
                              void* d_out, int out_size, void* d_ws, size_t ws_size,
                              hipStream_t stream) {
    const float* mesh = (const float*)d_in[0];  // [4][10242][64]
    const float* mv   = (const float*)d_in[1];  // [10242][3]
    const float* lat  = (const float*)d_in[2];  // [91]
    const float* lon  = (const float*)d_in[3];  // [180]
    const float* Wm   = (const float*)d_in[4];  // [64][64]
    const float* bias = (const float*)d_in[5];  // [64]
    float* out = (float*)d_out;                 // [4][64][91][180]

    float*  wts  = (float*)((char*)d_ws + WS_W_OFF);
    int*    nid  = (int*)((char*)d_ws + WS_I_OFF);
    float4* tbl  = (float4*)((char*)d_ws + WS_T_OFF);
    float*  slat = (float*)((char*)d_ws + WS_SL_OFF);
    int*    plat = (int*)((char*)d_ws + WS_PL_OFF);
    float*  slon = (float*)((char*)d_ws + WS_SO_OFF);
    int*    plon = (int*)((char*)d_ws + WS_PO_OFF);

    hipLaunchKernelGGL(build_table, dim3((N_PAD + 255) / 256), dim3(256), 0, stream,
                       mv, tbl);
    hipLaunchKernelGGL(sort_axes, dim3(1), dim3(256), 0, stream,
                       lat, lon, slat, plat, slon, plon);
    hipLaunchKernelGGL(knn_weights, dim3(NTI * NTJ), dim3(512), 0, stream,
                       slat, plat, slon, plon, tbl, wts, nid);
    hipLaunchKernelGGL(interp_apply, dim3(NBATCH * 256), dim3(256), 0, stream,
                       mesh, Wm, bias, wts, nid, out);
}

// Round 7
// 136.586 us; speedup vs baseline: 3.1493x; 1.2798x over previous
//
#include <hip/hip_runtime.h>
#include <math.h>

#define G_TOT   16380
#define N_NODES 10242
#define LATN    91
#define LONN    180
#define CH      64
#define NBATCH  4
#define KNN     8

#define NW      8                    // waves per knn block
#define N_PAD   (8 * 1312)           // 10496 sentinel-padded table (41*256)
#define CAP     1472                 // LDS candidate capacity (expected ~250)
#define TLA     8
#define TLO     8
#define NTI     ((LATN + TLA - 1) / TLA)   // 12
#define NTJ     ((LONN + TLO - 1) / TLO)   // 23

// search radius: chord^2 = 0.0144 (r=0.12). E[nodes inside]=36.9;
// P(8th-NN beyond r) ~ 2e-9/gp; brute-force fallback covers even that.
#define R2BOUND 0.0144f
#define RSNIP   0.121f               // r + slack for the patch filter

// workspace layout (bytes)
#define WS_W_OFF  0                            // float [G_TOT][8] weights
#define WS_I_OFF  (G_TOT * KNN * 4)            // int   [G_TOT][8] indices
#define WS_T_OFF  (2 * G_TOT * KNN * 4)        // float4[N_PAD]    node table
#define WS_SL_OFF (WS_T_OFF + N_PAD * 16)      // float [91]  sorted lat
#define WS_PL_OFF (WS_SL_OFF + LATN * 4)       // int   [91]  lat perm
#define WS_SO_OFF (WS_PL_OFF + LATN * 4)       // float [180] sorted lon
#define WS_PO_OFF (WS_SO_OFF + LONN * 4)       // int   [180] lon perm

// ---------------------------------------------------------------------------
// kernel 0 (fused prep): blocks 0..40 build the node table; block 41 ranks
// lat, block 42 ranks lon (O(n^2) counting sort: 1 barrier, not 271).
// Table: {x,y,z,m2}, m2 np-f32 style (no FMA). Sentinel pad (2,0,0,4):
// d2 >= 1 from any on-sphere point -> never accepted.
// ---------------------------------------------------------------------------
__global__ __launch_bounds__(256) void prep(const float* __restrict__ mv,
                                            float4* __restrict__ tbl,
                                            const float* __restrict__ lat,
                                            const float* __restrict__ lon,
                                            float* __restrict__ slat,
                                            int* __restrict__ plat,
                                            float* __restrict__ slon,
                                            int* __restrict__ plon) {
    const int blk = blockIdx.x, t = threadIdx.x;
    if (blk < 41) {
        int i = blk * 256 + t;  // 41*256 == N_PAD exactly
        if (i < N_NODES) {
            float x = mv[3 * i + 0], y = mv[3 * i + 1], z = mv[3 * i + 2];
            float m2 = __fadd_rn(__fadd_rn(__fmul_rn(x, x), __fmul_rn(y, y)),
                                 __fmul_rn(z, z));
            tbl[i] = make_float4(x, y, z, m2);
        } else {
            tbl[i] = make_float4(2.0f, 0.0f, 0.0f, 4.0f);
        }
    } else {
        __shared__ float sv[LONN];
        const bool  isla = (blk == 41);
        const int   n    = isla ? LATN : LONN;
        const float* arr = isla ? lat : lon;
        float* so = isla ? slat : slon;
        int*   po = isla ? plat : plon;
        if (t < n) sv[t] = arr[t];
        __syncthreads();
        if (t < n) {
            float v = sv[t];
            int r = 0;
            for (int j = 0; j < n; ++j)
                r += (sv[j] < v) || (sv[j] == v && j < t);
            so[r] = v;
            po[r] = t;
        }
    }
}

// ---------------------------------------------------------------------------
// kernel 1: spatial-patch KNN (unchanged from R6). One block per 8x8
// sorted-rank patch (276). Phase A: 512-thread coalesced compaction of nodes
// within R_patch+RSNIP of center into LDS. Phase B: 8 waves, lane = gp, scan
// compacted list with np-f32-exact key
//   d2  = fsub(fadd(g2,m2), fma(az,mz, fma(ay,my, mul(ax,mx))))
//   key = (bits(sqrtf(max(d2,1e-12))) << 32) | idx
// Fallbacks: LDS overflow -> full-table scan; <8 found -> per-gp brute scan.
// ---------------------------------------------------------------------------
__global__ __launch_bounds__(512) void knn_weights(const float* __restrict__ slat,
                                                   const int* __restrict__ plat,
                                                   const float* __restrict__ slon,
                                                   const int* __restrict__ plon,
                                                   const float4* __restrict__ tbl,
                                                   float* __restrict__ wts,
                                                   int* __restrict__ nidx) {
    __shared__ float4             cand[CAP];
    __shared__ int                cidx[CAP];
    __shared__ unsigned long long lists[NW][64][KNN];
    __shared__ float4             gpp[64];
    __shared__ int                gorig[64];
    __shared__ int                cnt;
    __shared__ float              r2tot;

    const int t  = threadIdx.x;
    const int gl = t & 63;
    const int w  = __builtin_amdgcn_readfirstlane(t >> 6);
    const int ti = blockIdx.x / NTJ, tj = blockIdx.x % NTJ;

    if (t < 64) {
        if (t == 0) cnt = 0;
        int ar = ti * TLA + (t >> 3), orr = tj * TLO + (t & 7);
        bool val = (ar < LATN) && (orr < LONN);
        int a = min(ar, LATN - 1), o = min(orr, LONN - 1);
        double dla = (double)slat[a], dlo = (double)slon[o];
        float cl = (float)cos(dla), sl = (float)sin(dla);
        float co = (float)cos(dlo), so = (float)sin(dlo);
        float gx = __fmul_rn(cl, co), gy = __fmul_rn(cl, so), gz = sl;
        float g2 = __fadd_rn(__fadd_rn(__fmul_rn(gx, gx), __fmul_rn(gy, gy)),
                             __fmul_rn(gz, gz));
        gpp[t]   = make_float4(gx, gy, gz, g2);
        gorig[t] = val ? (plat[a] * LONN + plon[o]) : -1;
    }
    __syncthreads();
    if (t < 64) {
        float4 c = gpp[27];
        float4 g = gpp[t];
        float dx = g.x - c.x, dy = g.y - c.y, dz = g.z - c.z;
        float d2c = dx * dx + dy * dy + dz * dz;
#pragma unroll
        for (int off = 32; off > 0; off >>= 1)
            d2c = fmaxf(d2c, __shfl_xor(d2c, off));
        if (t == 0) {
            float R = sqrtf(d2c) + RSNIP;
            r2tot = R * R + 1e-3f;
        }
    }
    __syncthreads();

    {
        float4 c = gpp[27];
        float r2t = r2tot;
        for (int j = t; j < N_NODES; j += 512) {
            float4 nd = tbl[j];
            float dx = nd.x - c.x, dy = nd.y - c.y, dz = nd.z - c.z;
            float d2c = dx * dx + dy * dy + dz * dz;
            if (d2c <= r2t) {
                int pos = atomicAdd(&cnt, 1);
                if (pos < CAP) { cand[pos] = nd; cidx[pos] = j; }
            }
        }
    }
    __syncthreads();
    const int  ncand = cnt;
    const bool ovf   = ncand > CAP;

    const float4 gme = gpp[gl];
    const float  gx = gme.x, gy = gme.y, gz = gme.z, g2 = gme.w;
    const float  ax = 2.0f * gx, ay = 2.0f * gy, az = 2.0f * gz;

    unsigned long long kk[KNN];
#pragma unroll
    for (int q = 0; q < KNN; ++q) kk[q] = ~0ull;

    if (!ovf) {
        const int nn = ncand;
        for (int ci = w; ci < nn; ci += NW) {
            float4 nd = cand[ci];
            int    j  = cidx[ci];
            float dot2 = __fmaf_rn(az, nd.z,
                          __fmaf_rn(ay, nd.y, __fmul_rn(ax, nd.x)));
            float d2 = __fsub_rn(__fadd_rn(g2, nd.w), dot2);
            if (d2 <= R2BOUND) {
                float sq = sqrtf(fmaxf(d2, 1e-12f));
                unsigned long long key =
                    ((unsigned long long)__float_as_uint(sq) << 32) |
                    (unsigned long long)(unsigned)j;
                if (key < kk[KNN - 1]) {
                    kk[KNN - 1] = key;
#pragma unroll
                    for (int q = KNN - 1; q > 0; --q) {
                        unsigned long long a = kk[q - 1], c = kk[q];
                        bool m = c < a;
                        kk[q - 1] = m ? c : a;
                        kk[q]     = m ? a : c;
                    }
                }
            }
        }
    } else {
        for (int j = w * 1312; j < (w + 1) * 1312; ++j) {
            float4 nd = tbl[j];
            float dot2 = __fmaf_rn(az, nd.z,
                          __fmaf_rn(ay, nd.y, __fmul_rn(ax, nd.x)));
            float d2 = __fsub_rn(__fadd_rn(g2, nd.w), dot2);
            if (d2 <= R2BOUND) {
                float sq = sqrtf(fmaxf(d2, 1e-12f));
                unsigned long long key =
                    ((unsigned long long)__float_as_uint(sq) << 32) |
                    (unsigned long long)(unsigned)j;
                if (key < kk[KNN - 1]) {
                    kk[KNN - 1] = key;
#pragma unroll
                    for (int q = KNN - 1; q > 0; --q) {
                        unsigned long long a = kk[q - 1], c = kk[q];
                        bool m = c < a;
                        kk[q - 1] = m ? c : a;
                        kk[q]     = m ? a : c;
                    }
                }
            }
        }
    }

#pragma unroll
    for (int q = 0; q < KNN; ++q) lists[w][gl][q] = kk[q];
    __syncthreads();

    if (t < 64) {
        int g = gorig[t];
        if (g >= 0) {
            int pos[NW];
#pragma unroll
            for (int s = 0; s < NW; ++s) pos[s] = 0;
            float dist[KNN];
            int   idxs[KNN];
            bool  bad = false;
            for (int r = 0; r < KNN; ++r) {
                unsigned long long best = ~0ull;
                int bs = 0;
#pragma unroll
                for (int s = 0; s < NW; ++s) {
                    unsigned long long v = (pos[s] < KNN) ? lists[s][t][pos[s]] : ~0ull;
                    if (v < best) { best = v; bs = s; }
                }
                if (best == ~0ull) bad = true;
                dist[r] = __uint_as_float((unsigned)(best >> 32));
                idxs[r] = (int)(best & 0xFFFFFFFFULL);
#pragma unroll
                for (int s = 0; s < NW; ++s) pos[s] += (s == bs) ? 1 : 0;
            }
            if (bad) {
                float4 gm = gpp[t];
                float bx = 2.0f * gm.x, by = 2.0f * gm.y, bz = 2.0f * gm.z;
                unsigned long long mm[KNN];
#pragma unroll
                for (int q = 0; q < KNN; ++q) mm[q] = ~0ull;
                for (int j = 0; j < N_NODES; ++j) {
                    float4 nd = tbl[j];
                    float dot2 = __fmaf_rn(bz, nd.z,
                                  __fmaf_rn(by, nd.y, __fmul_rn(bx, nd.x)));
                    float d2 = __fsub_rn(__fadd_rn(gm.w, nd.w), dot2);
                    float sq = sqrtf(fmaxf(d2, 1e-12f));
                    unsigned long long key =
                        ((unsigned long long)__float_as_uint(sq) << 32) |
                        (unsigned long long)(unsigned)j;
                    if (key < mm[KNN - 1]) {
                        mm[KNN - 1] = key;
#pragma unroll
                        for (int q = KNN - 1; q > 0; --q) {
                            unsigned long long a = mm[q - 1], c = mm[q];
                            bool m = c < a;
                            mm[q - 1] = m ? c : a;
                            mm[q]     = m ? a : c;
                        }
                    }
                }
#pragma unroll
                for (int r = 0; r < KNN; ++r) {
                    dist[r] = __uint_as_float((unsigned)(mm[r] >> 32));
                    idxs[r] = (int)(mm[r] & 0xFFFFFFFFULL);
                }
            }
            float e[KNN];
            float ssum = 0.f;
#pragma unroll
            for (int r = 0; r < KNN; ++r) {
                e[r] = expf(dist[0] - dist[r]);
                ssum += e[r];
            }
#pragma unroll
            for (int r = 0; r < KNN; ++r) {
                wts[g * KNN + r]  = e[r] / ssum;
                nidx[g * KNN + r] = idxs[r];
            }
        }
    }
}

// ---------------------------------------------------------------------------
// kernel 2: gather + weighted sum -> h, then y = W h + b, transposed store.
// R7 rewrite of the gather phase:
//  - prefetch all 512 (idx,wt) of the tile into LDS in one coalesced pass
//    (removes the per-iteration dependent s_load chains of R6)
//  - float4 gather: lane = (row-quad q, float4-chunk cq); one load instr
//    fetches 4 mesh rows x 16 float4 = 1 KB; 32 loads/wave vs 128, k-loop
//    gives 8 independent loads in flight.
// LDS h tile stride 65 (2-way bank aliasing = free). Phase 2 unchanged.
// ---------------------------------------------------------------------------
__global__ __launch_bounds__(256) void interp_apply(const float* __restrict__ mesh,
                                                    const float* __restrict__ Wm,
                                                    const float* __restrict__ bias,
                                                    const float* __restrict__ wts,
                                                    const int* __restrict__ nidx,
                                                    float* __restrict__ out) {
    __shared__ float hlds[64 * 65];
    __shared__ int   lidx[64 * KNN];
    __shared__ float lwt[64 * KNN];
    const int tile = blockIdx.x & 255;
    const int b    = blockIdx.x >> 8;
    const int t  = threadIdx.x;
    const int wv = __builtin_amdgcn_readfirstlane(t >> 6);
    const int ln = t & 63;
    const int g0 = tile * 64;

    // prefetch (idx, wt) for the whole tile: 512 entries, coalesced
#pragma unroll
    for (int r = 0; r < 2; ++r) {
        int e  = r * 256 + t;
        int gc = min(g0 + (e >> 3), G_TOT - 1);
        int s  = gc * KNN + (e & 7);
        lidx[e] = nidx[s];
        lwt[e]  = wts[s];
    }
    __syncthreads();

    // gather: lane = (q, cq); wave covers 4 rows per load instruction
    const int q  = ln >> 4, cq = ln & 15;
    const float4* meshb = (const float4*)(mesh + (size_t)b * N_NODES * CH);
#pragma unroll
    for (int gi = 0; gi < 4; ++gi) {
        int gp = wv * 16 + gi * 4 + q;
        float4 acc = make_float4(0.f, 0.f, 0.f, 0.f);
#pragma unroll
        for (int k = 0; k < KNN; ++k) {
            int   id = lidx[gp * KNN + k];
            float wk = lwt[gp * KNN + k];
            float4 row = meshb[(size_t)id * 16 + cq];
            acc.x = fmaf(wk, row.x, acc.x);
            acc.y = fmaf(wk, row.y, acc.y);
            acc.z = fmaf(wk, row.z, acc.z);
            acc.w = fmaf(wk, row.w, acc.w);
        }
        int base = gp * 65 + cq * 4;
        hlds[base + 0] = acc.x;
        hlds[base + 1] = acc.y;
        hlds[base + 2] = acc.z;
        hlds[base + 3] = acc.w;
    }
    __syncthreads();

    float h[CH];
#pragma unroll
    for (int c = 0; c < CH; ++c) h[c] = hlds[ln * 65 + c];
    int g = g0 + ln;
    if (g < G_TOT) {
#pragma unroll 1
        for (int cs = 0; cs < 16; ++cs) {
            int cp = wv * 16 + cs;
            float y = bias[cp];
#pragma unroll
            for (int c = 0; c < CH; ++c) y = fmaf(Wm[cp * CH + c], h[c], y);  // W uniform -> s_load
            out[((size_t)b * CH + cp) * G_TOT + g] = y;
        }
    }
}

// ---------------------------------------------------------------------------
extern "C" void kernel_launch(void* const* d_in, const int* in_sizes, int n_in,
                              void* d_out, int out_size, void* d_ws, size_t ws_size,
                              hipStream_t stream) {
    const float* mesh = (const float*)d_in[0];  // [4][10242][64]
    const float* mv   = (const float*)d_in[1];  // [10242][3]
    const float* lat  = (const float*)d_in[2];  // [91]
    const float* lon  = (const float*)d_in[3];  // [180]
    const float* Wm   = (const float*)d_in[4];  // [64][64]
    const float* bias = (const float*)d_in[5];  // [64]
    float* out = (float*)d_out;                 // [4][64][91][180]

    float*  wts  = (float*)((char*)d_ws + WS_W_OFF);
    int*    nid  = (int*)((char*)d_ws + WS_I_OFF);
    float4* tbl  = (float4*)((char*)d_ws + WS_T_OFF);
    float*  slat = (float*)((char*)d_ws + WS_SL_OFF);
    int*    plat = (int*)((char*)d_ws + WS_PL_OFF);
    float*  slon = (float*)((char*)d_ws + WS_SO_OFF);
    int*    plon = (int*)((char*)d_ws + WS_PO_OFF);

    hipLaunchKernelGGL(prep, dim3(43), dim3(256), 0, stream,
                       mv, tbl, lat, lon, slat, plat, slon, plon);
    hipLaunchKernelGGL(knn_weights, dim3(NTI * NTJ), dim3(512), 0, stream,
                       slat, plat, slon, plon, tbl, wts, nid);
    hipLaunchKernelGGL(interp_apply, dim3(NBATCH * 256), dim3(256), 0, stream,
                       mesh, Wm, bias, wts, nid, out);
}

// Round 9
// 131.188 us; speedup vs baseline: 3.2789x; 1.0411x over previous
//
#include <hip/hip_runtime.h>
#include <math.h>

#define G_TOT   16380
#define N_NODES 10242
#define LATN    91
#define LONN    180
#define CH      64
#define NBATCH  4
#define KNN     8

#define NW      8                    // waves per knn block
#define N_PAD   (8 * 1312)           // 10496 sentinel-padded table (41*256)
#define CAP     1472                 // LDS candidate capacity (expected ~300)
#define TLA     8
#define TLO     8
#define NTI     12                   // ceil(91/8)
#define NTJ     23                   // ceil(180/8)

// search radius: chord^2 = 0.0144 (r=0.12). E[nodes inside]=36.9;
// P(8th-NN beyond r) ~ 2e-9/gp; full-table fallback covers even that.
#define R2BOUND 0.0144f
#define RSNIP   0.121f               // r + slack for the patch filter

// workspace layout (bytes)
#define WS_W_OFF  0                            // float [G_TOT][8] weights
#define WS_I_OFF  (G_TOT * KNN * 4)            // int   [G_TOT][8] indices
#define WS_T_OFF  (2 * G_TOT * KNN * 4)        // float4[N_PAD]    node table
#define WS_SL_OFF (WS_T_OFF + N_PAD * 16)      // float [91]  sorted lat
#define WS_PL_OFF (WS_SL_OFF + LATN * 4)       // int   [91]  lat perm
#define WS_SO_OFF (WS_PL_OFF + LATN * 4)       // float [180] sorted lon
#define WS_PO_OFF (WS_SO_OFF + LONN * 4)       // int   [180] lon perm
#define WS_M2_OFF ((WS_PO_OFF + LONN * 4 + 15) & ~15)  // float [4][N_NODES][64]

// ---------------------------------------------------------------------------
// kernel 0 (fused prep): blocks 0..40 node table; block 41 ranks lat,
// block 42 ranks lon (O(n^2) counting rank, 1 barrier).
// Table: {x,y,z,m2}, m2 np-f32 style (no FMA). Sentinel pad (2,0,0,4).
// ---------------------------------------------------------------------------
__global__ __launch_bounds__(256) void prep(const float* __restrict__ mv,
                                            float4* __restrict__ tbl,
                                            const float* __restrict__ lat,
                                            const float* __restrict__ lon,
                                            float* __restrict__ slat,
                                            int* __restrict__ plat,
                                            float* __restrict__ slon,
                                            int* __restrict__ plon) {
    const int blk = blockIdx.x, t = threadIdx.x;
    if (blk < 41) {
        int i = blk * 256 + t;  // 41*256 == N_PAD
        if (i < N_NODES) {
            float x = mv[3 * i + 0], y = mv[3 * i + 1], z = mv[3 * i + 2];
            float m2 = __fadd_rn(__fadd_rn(__fmul_rn(x, x), __fmul_rn(y, y)),
                                 __fmul_rn(z, z));
            tbl[i] = make_float4(x, y, z, m2);
        } else {
            tbl[i] = make_float4(2.0f, 0.0f, 0.0f, 4.0f);
        }
    } else {
        __shared__ float sv[LONN];
        const bool  isla = (blk == 41);
        const int   n    = isla ? LATN : LONN;
        const float* arr = isla ? lat : lon;
        float* so = isla ? slat : slon;
        int*   po = isla ? plat : plon;
        if (t < n) sv[t] = arr[t];
        __syncthreads();
        if (t < n) {
            float v = sv[t];
            int r = 0;
            for (int j = 0; j < n; ++j)
                r += (sv[j] < v) || (sv[j] == v && j < t);
            so[r] = v;
            po[r] = t;
        }
    }
}

// ---------------------------------------------------------------------------
// kernel 1: spatial-patch KNN — EXACT R7 source (passed twice). R8's
// bucket-collect rewrite produced a one-neighbor flip (absmax 0.59) I could
// not prove equivalent; reverted bit-for-bit. DO NOT touch selection logic
// without an A/B against this version.
// ---------------------------------------------------------------------------
__global__ __launch_bounds__(512) void knn_weights(const float* __restrict__ slat,
                                                   const int* __restrict__ plat,
                                                   const float* __restrict__ slon,
                                                   const int* __restrict__ plon,
                                                   const float4* __restrict__ tbl,
                                                   float* __restrict__ wts,
                                                   int* __restrict__ nidx) {
    __shared__ float4             cand[CAP];
    __shared__ int                cidx[CAP];
    __shared__ unsigned long long lists[NW][64][KNN];
    __shared__ float4             gpp[64];
    __shared__ int                gorig[64];
    __shared__ int                cnt;
    __shared__ float              r2tot;

    const int t  = threadIdx.x;
    const int gl = t & 63;
    const int w  = __builtin_amdgcn_readfirstlane(t >> 6);
    const int ti = blockIdx.x / NTJ, tj = blockIdx.x % NTJ;

    if (t < 64) {
        if (t == 0) cnt = 0;
        int ar = ti * TLA + (t >> 3), orr = tj * TLO + (t & 7);
        bool val = (ar < LATN) && (orr < LONN);
        int a = min(ar, LATN - 1), o = min(orr, LONN - 1);
        double dla = (double)slat[a], dlo = (double)slon[o];
        float cl = (float)cos(dla), sl = (float)sin(dla);
        float co = (float)cos(dlo), so = (float)sin(dlo);
        float gx = __fmul_rn(cl, co), gy = __fmul_rn(cl, so), gz = sl;
        float g2 = __fadd_rn(__fadd_rn(__fmul_rn(gx, gx), __fmul_rn(gy, gy)),
                             __fmul_rn(gz, gz));
        gpp[t]   = make_float4(gx, gy, gz, g2);
        gorig[t] = val ? (plat[a] * LONN + plon[o]) : -1;
    }
    __syncthreads();
    if (t < 64) {
        float4 c = gpp[27];
        float4 g = gpp[t];
        float dx = g.x - c.x, dy = g.y - c.y, dz = g.z - c.z;
        float d2c = dx * dx + dy * dy + dz * dz;
#pragma unroll
        for (int off = 32; off > 0; off >>= 1)
            d2c = fmaxf(d2c, __shfl_xor(d2c, off));
        if (t == 0) {
            float R = sqrtf(d2c) + RSNIP;
            r2tot = R * R + 1e-3f;
        }
    }
    __syncthreads();

    {
        float4 c = gpp[27];
        float r2t = r2tot;
        for (int j = t; j < N_NODES; j += 512) {
            float4 nd = tbl[j];
            float dx = nd.x - c.x, dy = nd.y - c.y, dz = nd.z - c.z;
            float d2c = dx * dx + dy * dy + dz * dz;
            if (d2c <= r2t) {
                int pos = atomicAdd(&cnt, 1);
                if (pos < CAP) { cand[pos] = nd; cidx[pos] = j; }
            }
        }
    }
    __syncthreads();
    const int  ncand = cnt;
    const bool ovf   = ncand > CAP;

    const float4 gme = gpp[gl];
    const float  gx = gme.x, gy = gme.y, gz = gme.z, g2 = gme.w;
    const float  ax = 2.0f * gx, ay = 2.0f * gy, az = 2.0f * gz;

    unsigned long long kk[KNN];
#pragma unroll
    for (int q = 0; q < KNN; ++q) kk[q] = ~0ull;

    if (!ovf) {
        const int nn = ncand;
        for (int ci = w; ci < nn; ci += NW) {
            float4 nd = cand[ci];
            int    j  = cidx[ci];
            float dot2 = __fmaf_rn(az, nd.z,
                          __fmaf_rn(ay, nd.y, __fmul_rn(ax, nd.x)));
            float d2 = __fsub_rn(__fadd_rn(g2, nd.w), dot2);
            if (d2 <= R2BOUND) {
                float sq = sqrtf(fmaxf(d2, 1e-12f));
                unsigned long long key =
                    ((unsigned long long)__float_as_uint(sq) << 32) |
                    (unsigned long long)(unsigned)j;
                if (key < kk[KNN - 1]) {
                    kk[KNN - 1] = key;
#pragma unroll
                    for (int q = KNN - 1; q > 0; --q) {
                        unsigned long long a = kk[q - 1], c = kk[q];
                        bool m = c < a;
                        kk[q - 1] = m ? c : a;
                        kk[q]     = m ? a : c;
                    }
                }
            }
        }
    } else {
        for (int j = w * 1312; j < (w + 1) * 1312; ++j) {
            float4 nd = tbl[j];
            float dot2 = __fmaf_rn(az, nd.z,
                          __fmaf_rn(ay, nd.y, __fmul_rn(ax, nd.x)));
            float d2 = __fsub_rn(__fadd_rn(g2, nd.w), dot2);
            if (d2 <= R2BOUND) {
                float sq = sqrtf(fmaxf(d2, 1e-12f));
                unsigned long long key =
                    ((unsigned long long)__float_as_uint(sq) << 32) |
                    (unsigned long long)(unsigned)j;
                if (key < kk[KNN - 1]) {
                    kk[KNN - 1] = key;
#pragma unroll
                    for (int q = KNN - 1; q > 0; --q) {
                        unsigned long long a = kk[q - 1], c = kk[q];
                        bool m = c < a;
                        kk[q - 1] = m ? c : a;
                        kk[q]     = m ? a : c;
                    }
                }
            }
        }
    }

#pragma unroll
    for (int q = 0; q < KNN; ++q) lists[w][gl][q] = kk[q];
    __syncthreads();

    if (t < 64) {
        int g = gorig[t];
        if (g >= 0) {
            int pos[NW];
#pragma unroll
            for (int s = 0; s < NW; ++s) pos[s] = 0;
            float dist[KNN];
            int   idxs[KNN];
            bool  bad = false;
            for (int r = 0; r < KNN; ++r) {
                unsigned long long best = ~0ull;
                int bs = 0;
#pragma unroll
                for (int s = 0; s < NW; ++s) {
                    unsigned long long v = (pos[s] < KNN) ? lists[s][t][pos[s]] : ~0ull;
                    if (v < best) { best = v; bs = s; }
                }
                if (best == ~0ull) bad = true;
                dist[r] = __uint_as_float((unsigned)(best >> 32));
                idxs[r] = (int)(best & 0xFFFFFFFFULL);
#pragma unroll
                for (int s = 0; s < NW; ++s) pos[s] += (s == bs) ? 1 : 0;
            }
            if (bad) {
                float4 gm = gpp[t];
                float bx = 2.0f * gm.x, by = 2.0f * gm.y, bz = 2.0f * gm.z;
                unsigned long long mm[KNN];
#pragma unroll
                for (int q = 0; q < KNN; ++q) mm[q] = ~0ull;
                for (int j = 0; j < N_NODES; ++j) {
                    float4 nd = tbl[j];
                    float dot2 = __fmaf_rn(bz, nd.z,
                                  __fmaf_rn(by, nd.y, __fmul_rn(bx, nd.x)));
                    float d2 = __fsub_rn(__fadd_rn(gm.w, nd.w), dot2);
                    float sq = sqrtf(fmaxf(d2, 1e-12f));
                    unsigned long long key =
                        ((unsigned long long)__float_as_uint(sq) << 32) |
                        (unsigned long long)(unsigned)j;
                    if (key < mm[KNN - 1]) {
                        mm[KNN - 1] = key;
#pragma unroll
                        for (int q = KNN - 1; q > 0; --q) {
                            unsigned long long a = mm[q - 1], c = mm[q];
                            bool m = c < a;
                            mm[q - 1] = m ? c : a;
                            mm[q]     = m ? a : c;
                        }
                    }
                }
#pragma unroll
                for (int r = 0; r < KNN; ++r) {
                    dist[r] = __uint_as_float((unsigned)(mm[r] >> 32));
                    idxs[r] = (int)(mm[r] & 0xFFFFFFFFULL);
                }
            }
            float e[KNN];
            float ssum = 0.f;
#pragma unroll
            for (int r = 0; r < KNN; ++r) {
                e[r] = expf(dist[0] - dist[r]);
                ssum += e[r];
            }
#pragma unroll
            for (int r = 0; r < KNN; ++r) {
                wts[g * KNN + r]  = e[r] / ssum;
                nidx[g * KNN + r] = idxs[r];
            }
        }
    }
}

// ---------------------------------------------------------------------------
// kernel 2: mesh2 = mesh @ W^T + bias (per batch). Register-tiled 4x4,
// both operands LDS-transposed to c-major for b128 reads. stride 68: 16B
// aligned. Error vs ref's (interp then matmul) order: ~1e-5 << 0.038.
// ---------------------------------------------------------------------------
__global__ __launch_bounds__(256) void gemm_w(const float* __restrict__ mesh,
                                              const float* __restrict__ Wm,
                                              const float* __restrict__ bias,
                                              float* __restrict__ mesh2) {
    __shared__ float amT[64][68];  // amT[c][row]
    __shared__ float wtT[64][68];  // wtT[c][cp]
    const int t    = threadIdx.x;
    const int b    = blockIdx.x / 161;
    const int row0 = (blockIdx.x % 161) * 64;
    const float* mb = mesh + (size_t)b * N_NODES * CH;

#pragma unroll
    for (int k = 0; k < 4; ++k) {
        int e = k * 256 + t;
        int r = e >> 4, c4 = e & 15;
        int row = row0 + r;
        float4 v = make_float4(0.f, 0.f, 0.f, 0.f);
        if (row < N_NODES) v = *(const float4*)&mb[(size_t)row * CH + c4 * 4];
        amT[c4 * 4 + 0][r] = v.x;
        amT[c4 * 4 + 1][r] = v.y;
        amT[c4 * 4 + 2][r] = v.z;
        amT[c4 * 4 + 3][r] = v.w;
        float4 wv = *(const float4*)&Wm[r * CH + c4 * 4];  // r == cp here
        wtT[c4 * 4 + 0][r] = wv.x;
        wtT[c4 * 4 + 1][r] = wv.y;
        wtT[c4 * 4 + 2][r] = wv.z;
        wtT[c4 * 4 + 3][r] = wv.w;
    }
    __syncthreads();

    const int tr = t & 15, tc = t >> 4;
    const int r0 = tr * 4, cp0 = tc * 4;
    float acc[4][4];
#pragma unroll
    for (int i = 0; i < 4; ++i)
#pragma unroll
        for (int j = 0; j < 4; ++j) acc[i][j] = 0.f;

    for (int c = 0; c < 64; ++c) {
        float4 av = *(const float4*)&amT[c][r0];
        float4 wv = *(const float4*)&wtT[c][cp0];
        float a4[4] = {av.x, av.y, av.z, av.w};
        float w4[4] = {wv.x, wv.y, wv.z, wv.w};
#pragma unroll
        for (int i = 0; i < 4; ++i)
#pragma unroll
            for (int j = 0; j < 4; ++j)
                acc[i][j] = fmaf(a4[i], w4[j], acc[i][j]);
    }

    float4 bv = *(const float4*)&bias[cp0];
#pragma unroll
    for (int i = 0; i < 4; ++i) {
        int row = row0 + r0 + i;
        if (row < N_NODES) {
            float4 o = make_float4(acc[i][0] + bv.x, acc[i][1] + bv.y,
                                   acc[i][2] + bv.z, acc[i][3] + bv.w);
            *(float4*)&mesh2[((size_t)b * N_NODES + row) * CH + cp0] = o;
        }
    }
}

// ---------------------------------------------------------------------------
// kernel 3: out[b,cp,g] = sum_k w_k * mesh2[b,idx_k,cp]  (bias folded into
// mesh2 since sum_k w_k == 1). Pure gather + LDS transpose + coalesced store.
// No per-thread h[64] -> R7 interp's 1024-ds_read/thread pathology gone.
// ---------------------------------------------------------------------------
__global__ __launch_bounds__(256) void interp_gather(const float* __restrict__ mesh2,
                                                     const float* __restrict__ wts,
                                                     const int* __restrict__ nidx,
                                                     float* __restrict__ out) {
    __shared__ float lds2[64][66];  // [cp][g]
    __shared__ int   lidx[512];
    __shared__ float lwt[512];
    const int tile = blockIdx.x & 255;
    const int b    = blockIdx.x >> 8;
    const int t  = threadIdx.x;
    const int wv = __builtin_amdgcn_readfirstlane(t >> 6);
    const int ln = t & 63;
    const int g0 = tile * 64;

#pragma unroll
    for (int r = 0; r < 2; ++r) {
        int e  = r * 256 + t;
        int gc = min(g0 + (e >> 3), G_TOT - 1);
        int s  = gc * KNN + (e & 7);
        lidx[e] = nidx[s];
        lwt[e]  = wts[s];
    }
    __syncthreads();

    const float* m2b = mesh2 + (size_t)b * N_NODES * CH;
#pragma unroll 4
    for (int gi = 0; gi < 16; ++gi) {
        int gloc = wv * 16 + gi;
        float acc = 0.f;
#pragma unroll
        for (int k = 0; k < KNN; ++k) {
            int   id = lidx[gloc * KNN + k];
            float wk = lwt[gloc * KNN + k];
            acc = fmaf(wk, m2b[(size_t)id * CH + ln], acc);  // 256B/wave, ILP 8
        }
        lds2[ln][gloc] = acc;
    }
    __syncthreads();

    int g = g0 + ln;
    if (g < G_TOT) {
#pragma unroll
        for (int cs = 0; cs < 16; ++cs) {
            int cp = wv * 16 + cs;
            out[((size_t)b * CH + cp) * G_TOT + g] = lds2[cp][ln];
        }
    }
}

// ---------------------------------------------------------------------------
extern "C" void kernel_launch(void* const* d_in, const int* in_sizes, int n_in,
                              void* d_out, int out_size, void* d_ws, size_t ws_size,
                              hipStream_t stream) {
    const float* mesh = (const float*)d_in[0];  // [4][10242][64]
    const float* mv   = (const float*)d_in[1];  // [10242][3]
    const float* lat  = (const float*)d_in[2];  // [91]
    const float* lon  = (const float*)d_in[3];  // [180]
    const float* Wm   = (const float*)d_in[4];  // [64][64]
    const float* bias = (const float*)d_in[5];  // [64]
    float* out = (float*)d_out;                 // [4][64][91][180]

    float*  wts  = (float*)((char*)d_ws + WS_W_OFF);
    int*    nid  = (int*)((char*)d_ws + WS_I_OFF);
    float4* tbl  = (float4*)((char*)d_ws + WS_T_OFF);
    float*  slat = (float*)((char*)d_ws + WS_SL_OFF);
    int*    plat = (int*)((char*)d_ws + WS_PL_OFF);
    float*  slon = (float*)((char*)d_ws + WS_SO_OFF);
    int*    plon = (int*)((char*)d_ws + WS_PO_OFF);
    float*  m2   = (float*)((char*)d_ws + WS_M2_OFF);

    hipLaunchKernelGGL(prep, dim3(43), dim3(256), 0, stream,
                       mv, tbl, lat, lon, slat, plat, slon, plon);
    hipLaunchKernelGGL(knn_weights, dim3(NTI * NTJ), dim3(512), 0, stream,
                       slat, plat, slon, plon, tbl, wts, nid);
    hipLaunchKernelGGL(gemm_w, dim3(NBATCH * 161), dim3(256), 0, stream,
                       mesh, Wm, bias, m2);
    hipLaunchKernelGGL(interp_gather, dim3(NBATCH * 256), dim3(256), 0, stream,
                       m2, wts, nid, out);
}

// Round 10
// 123.727 us; speedup vs baseline: 3.4766x; 1.0603x over previous
//
#include <hip/hip_runtime.h>
#include <math.h>

#define G_TOT   16380
#define N_NODES 10242
#define LATN    91
#define LONN    180
#define CH      64
#define NBATCH  4
#define KNN     8

#define NW      8                    // waves per knn block
#define N_PAD   (8 * 1312)           // 10496 sentinel-padded table (41*256)
#define CAP     1472                 // LDS candidate capacity (expected ~300)
#define TLA     8
#define TLO     8
#define NTI     12                   // ceil(91/8)
#define NTJ     23                   // ceil(180/8)

// search radius: chord^2 = 0.0144 (r=0.12). E[nodes inside]=36.9;
// P(8th-NN beyond r) ~ 2e-9/gp; full-table fallback covers even that.
#define R2BOUND 0.0144f
#define RSNIP   0.121f               // r + slack for the patch filter

// workspace layout (bytes)
#define WS_W_OFF  0                            // float [G_TOT][8] weights
#define WS_I_OFF  (G_TOT * KNN * 4)            // int   [G_TOT][8] indices
#define WS_T_OFF  (2 * G_TOT * KNN * 4)        // float4[N_PAD]    node table
#define WS_SL_OFF (WS_T_OFF + N_PAD * 16)      // float [91]  sorted lat
#define WS_PL_OFF (WS_SL_OFF + LATN * 4)       // int   [91]  lat perm
#define WS_SO_OFF (WS_PL_OFF + LATN * 4)       // float [180] sorted lon
#define WS_PO_OFF (WS_SO_OFF + LONN * 4)       // int   [180] lon perm
#define WS_M2_OFF ((WS_PO_OFF + LONN * 4 + 15) & ~15)  // float [4][N_NODES][64]

// ---------------------------------------------------------------------------
// kernel 0 (fused prep + gemm): blocks 0..40 node table; block 41 ranks lat;
// block 42 ranks lon; blocks 43..686 compute mesh2 = mesh @ W^T + bias
// (independent of the prep outputs -> safe in one launch; saves a launch gap).
// Table: {x,y,z,m2}, m2 np-f32 style (no FMA). Sentinel pad (2,0,0,4).
// gemm: register-tiled 4x4, operands LDS-transposed c-major, stride 68.
// ---------------------------------------------------------------------------
__global__ __launch_bounds__(256) void prep_gemm(const float* __restrict__ mv,
                                                 float4* __restrict__ tbl,
                                                 const float* __restrict__ lat,
                                                 const float* __restrict__ lon,
                                                 float* __restrict__ slat,
                                                 int* __restrict__ plat,
                                                 float* __restrict__ slon,
                                                 int* __restrict__ plon,
                                                 const float* __restrict__ mesh,
                                                 const float* __restrict__ Wm,
                                                 const float* __restrict__ bias,
                                                 float* __restrict__ mesh2) {
    const int blk = blockIdx.x, t = threadIdx.x;
    if (blk < 41) {
        int i = blk * 256 + t;  // 41*256 == N_PAD
        if (i < N_NODES) {
            float x = mv[3 * i + 0], y = mv[3 * i + 1], z = mv[3 * i + 2];
            float m2 = __fadd_rn(__fadd_rn(__fmul_rn(x, x), __fmul_rn(y, y)),
                                 __fmul_rn(z, z));
            tbl[i] = make_float4(x, y, z, m2);
        } else {
            tbl[i] = make_float4(2.0f, 0.0f, 0.0f, 4.0f);
        }
    } else if (blk < 43) {
        __shared__ float sv[LONN];
        const bool  isla = (blk == 41);
        const int   n    = isla ? LATN : LONN;
        const float* arr = isla ? lat : lon;
        float* so = isla ? slat : slon;
        int*   po = isla ? plat : plon;
        if (t < n) sv[t] = arr[t];
        __syncthreads();
        if (t < n) {
            float v = sv[t];
            int r = 0;
            for (int j = 0; j < n; ++j)
                r += (sv[j] < v) || (sv[j] == v && j < t);
            so[r] = v;
            po[r] = t;
        }
    } else {
        __shared__ float amT[64][68];  // amT[c][row]
        __shared__ float wtT[64][68];  // wtT[c][cp]
        const int gb   = blk - 43;
        const int b    = gb / 161;
        const int row0 = (gb % 161) * 64;
        const float* mb = mesh + (size_t)b * N_NODES * CH;

#pragma unroll
        for (int k = 0; k < 4; ++k) {
            int e = k * 256 + t;
            int r = e >> 4, c4 = e & 15;
            int row = row0 + r;
            float4 v = make_float4(0.f, 0.f, 0.f, 0.f);
            if (row < N_NODES) v = *(const float4*)&mb[(size_t)row * CH + c4 * 4];
            amT[c4 * 4 + 0][r] = v.x;
            amT[c4 * 4 + 1][r] = v.y;
            amT[c4 * 4 + 2][r] = v.z;
            amT[c4 * 4 + 3][r] = v.w;
            float4 wv = *(const float4*)&Wm[r * CH + c4 * 4];  // r == cp here
            wtT[c4 * 4 + 0][r] = wv.x;
            wtT[c4 * 4 + 1][r] = wv.y;
            wtT[c4 * 4 + 2][r] = wv.z;
            wtT[c4 * 4 + 3][r] = wv.w;
        }
        __syncthreads();

        const int tr = t & 15, tc = t >> 4;
        const int r0 = tr * 4, cp0 = tc * 4;
        float acc[4][4];
#pragma unroll
        for (int i = 0; i < 4; ++i)
#pragma unroll
            for (int j = 0; j < 4; ++j) acc[i][j] = 0.f;

        for (int c = 0; c < 64; ++c) {
            float4 av = *(const float4*)&amT[c][r0];
            float4 wv = *(const float4*)&wtT[c][cp0];
            float a4[4] = {av.x, av.y, av.z, av.w};
            float w4[4] = {wv.x, wv.y, wv.z, wv.w};
#pragma unroll
            for (int i = 0; i < 4; ++i)
#pragma unroll
                for (int j = 0; j < 4; ++j)
                    acc[i][j] = fmaf(a4[i], w4[j], acc[i][j]);
        }

        float4 bv = *(const float4*)&bias[cp0];
#pragma unroll
        for (int i = 0; i < 4; ++i) {
            int row = row0 + r0 + i;
            if (row < N_NODES) {
                float4 o = make_float4(acc[i][0] + bv.x, acc[i][1] + bv.y,
                                       acc[i][2] + bv.z, acc[i][3] + bv.w);
                *(float4*)&mesh2[((size_t)b * N_NODES + row) * CH + cp0] = o;
            }
        }
    }
}

// ---------------------------------------------------------------------------
// kernel 1: spatial-patch KNN — R7 logic; ONLY change vs R9: phase A stages
// 4 loads before the filter/atomic (breaks the 20-deep dependent-load chain).
// This reorders cand[] pushes only; R7's push order was already
// nondeterministic (cross-wave atomics) and selection is an order-independent
// min-8 over exact u64 keys -> accepted set, ncand, and results identical.
// Phase B / merge / epilogue byte-for-byte R7. DO NOT touch selection logic
// without an A/B against this version (R8 lesson).
// ---------------------------------------------------------------------------
__global__ __launch_bounds__(512) void knn_weights(const float* __restrict__ slat,
                                                   const int* __restrict__ plat,
                                                   const float* __restrict__ slon,
                                                   const int* __restrict__ plon,
                                                   const float4* __restrict__ tbl,
                                                   float* __restrict__ wts,
                                                   int* __restrict__ nidx) {
    __shared__ float4             cand[CAP];
    __shared__ int                cidx[CAP];
    __shared__ unsigned long long lists[NW][64][KNN];
    __shared__ float4             gpp[64];
    __shared__ int                gorig[64];
    __shared__ int                cnt;
    __shared__ float              r2tot;

    const int t  = threadIdx.x;
    const int gl = t & 63;
    const int w  = __builtin_amdgcn_readfirstlane(t >> 6);
    const int ti = blockIdx.x / NTJ, tj = blockIdx.x % NTJ;

    if (t < 64) {
        if (t == 0) cnt = 0;
        int ar = ti * TLA + (t >> 3), orr = tj * TLO + (t & 7);
        bool val = (ar < LATN) && (orr < LONN);
        int a = min(ar, LATN - 1), o = min(orr, LONN - 1);
        double dla = (double)slat[a], dlo = (double)slon[o];
        float cl = (float)cos(dla), sl = (float)sin(dla);
        float co = (float)cos(dlo), so = (float)sin(dlo);
        float gx = __fmul_rn(cl, co), gy = __fmul_rn(cl, so), gz = sl;
        float g2 = __fadd_rn(__fadd_rn(__fmul_rn(gx, gx), __fmul_rn(gy, gy)),
                             __fmul_rn(gz, gz));
        gpp[t]   = make_float4(gx, gy, gz, g2);
        gorig[t] = val ? (plat[a] * LONN + plon[o]) : -1;
    }
    __syncthreads();
    if (t < 64) {
        float4 c = gpp[27];
        float4 g = gpp[t];
        float dx = g.x - c.x, dy = g.y - c.y, dz = g.z - c.z;
        float d2c = dx * dx + dy * dy + dz * dz;
#pragma unroll
        for (int off = 32; off > 0; off >>= 1)
            d2c = fmaxf(d2c, __shfl_xor(d2c, off));
        if (t == 0) {
            float R = sqrtf(d2c) + RSNIP;
            r2tot = R * R + 1e-3f;
        }
    }
    __syncthreads();

    // ---- phase A: compaction, loads staged 4-deep (R10 change)
    {
        float4 c = gpp[27];
        float r2t = r2tot;
        for (int j0 = t; j0 < N_NODES; j0 += 512 * 4) {
            float4 nd[4];
#pragma unroll
            for (int u = 0; u < 4; ++u) {
                int j = j0 + u * 512;
                nd[u] = (j < N_NODES) ? tbl[j] : make_float4(2.f, 0.f, 0.f, 4.f);
            }
#pragma unroll
            for (int u = 0; u < 4; ++u) {
                int j = j0 + u * 512;
                float dx = nd[u].x - c.x, dy = nd[u].y - c.y, dz = nd[u].z - c.z;
                float d2c = dx * dx + dy * dy + dz * dz;
                if (d2c <= r2t && j < N_NODES) {
                    int pos = atomicAdd(&cnt, 1);
                    if (pos < CAP) { cand[pos] = nd[u]; cidx[pos] = j; }
                }
            }
        }
    }
    __syncthreads();
    const int  ncand = cnt;
    const bool ovf   = ncand > CAP;

    const float4 gme = gpp[gl];
    const float  gx = gme.x, gy = gme.y, gz = gme.z, g2 = gme.w;
    const float  ax = 2.0f * gx, ay = 2.0f * gy, az = 2.0f * gz;

    unsigned long long kk[KNN];
#pragma unroll
    for (int q = 0; q < KNN; ++q) kk[q] = ~0ull;

    if (!ovf) {
        const int nn = ncand;
        for (int ci = w; ci < nn; ci += NW) {
            float4 nd = cand[ci];
            int    j  = cidx[ci];
            float dot2 = __fmaf_rn(az, nd.z,
                          __fmaf_rn(ay, nd.y, __fmul_rn(ax, nd.x)));
            float d2 = __fsub_rn(__fadd_rn(g2, nd.w), dot2);
            if (d2 <= R2BOUND) {
                float sq = sqrtf(fmaxf(d2, 1e-12f));
                unsigned long long key =
                    ((unsigned long long)__float_as_uint(sq) << 32) |
                    (unsigned long long)(unsigned)j;
                if (key < kk[KNN - 1]) {
                    kk[KNN - 1] = key;
#pragma unroll
                    for (int q = KNN - 1; q > 0; --q) {
                        unsigned long long a = kk[q - 1], c = kk[q];
                        bool m = c < a;
                        kk[q - 1] = m ? c : a;
                        kk[q]     = m ? a : c;
                    }
                }
            }
        }
    } else {
        for (int j = w * 1312; j < (w + 1) * 1312; ++j) {
            float4 nd = tbl[j];
            float dot2 = __fmaf_rn(az, nd.z,
                          __fmaf_rn(ay, nd.y, __fmul_rn(ax, nd.x)));
            float d2 = __fsub_rn(__fadd_rn(g2, nd.w), dot2);
            if (d2 <= R2BOUND) {
                float sq = sqrtf(fmaxf(d2, 1e-12f));
                unsigned long long key =
                    ((unsigned long long)__float_as_uint(sq) << 32) |
                    (unsigned long long)(unsigned)j;
                if (key < kk[KNN - 1]) {
                    kk[KNN - 1] = key;
#pragma unroll
                    for (int q = KNN - 1; q > 0; --q) {
                        unsigned long long a = kk[q - 1], c = kk[q];
                        bool m = c < a;
                        kk[q - 1] = m ? c : a;
                        kk[q]     = m ? a : c;
                    }
                }
            }
        }
    }

#pragma unroll
    for (int q = 0; q < KNN; ++q) lists[w][gl][q] = kk[q];
    __syncthreads();

    if (t < 64) {
        int g = gorig[t];
        if (g >= 0) {
            int pos[NW];
#pragma unroll
            for (int s = 0; s < NW; ++s) pos[s] = 0;
            float dist[KNN];
            int   idxs[KNN];
            bool  bad = false;
            for (int r = 0; r < KNN; ++r) {
                unsigned long long best = ~0ull;
                int bs = 0;
#pragma unroll
                for (int s = 0; s < NW; ++s) {
                    unsigned long long v = (pos[s] < KNN) ? lists[s][t][pos[s]] : ~0ull;
                    if (v < best) { best = v; bs = s; }
                }
                if (best == ~0ull) bad = true;
                dist[r] = __uint_as_float((unsigned)(best >> 32));
                idxs[r] = (int)(best & 0xFFFFFFFFULL);
#pragma unroll
                for (int s = 0; s < NW; ++s) pos[s] += (s == bs) ? 1 : 0;
            }
            if (bad) {
                float4 gm = gpp[t];
                float bx = 2.0f * gm.x, by = 2.0f * gm.y, bz = 2.0f * gm.z;
                unsigned long long mm[KNN];
#pragma unroll
                for (int q = 0; q < KNN; ++q) mm[q] = ~0ull;
                for (int j = 0; j < N_NODES; ++j) {
                    float4 nd = tbl[j];
                    float dot2 = __fmaf_rn(bz, nd.z,
                                  __fmaf_rn(by, nd.y, __fmul_rn(bx, nd.x)));
                    float d2 = __fsub_rn(__fadd_rn(gm.w, nd.w), dot2);
                    float sq = sqrtf(fmaxf(d2, 1e-12f));
                    unsigned long long key =
                        ((unsigned long long)__float_as_uint(sq) << 32) |
                        (unsigned long long)(unsigned)j;
                    if (key < mm[KNN - 1]) {
                        mm[KNN - 1] = key;
#pragma unroll
                        for (int q = KNN - 1; q > 0; --q) {
                            unsigned long long a = mm[q - 1], c = mm[q];
                            bool m = c < a;
                            mm[q - 1] = m ? c : a;
                            mm[q]     = m ? a : c;
                        }
                    }
                }
#pragma unroll
                for (int r = 0; r < KNN; ++r) {
                    dist[r] = __uint_as_float((unsigned)(mm[r] >> 32));
                    idxs[r] = (int)(mm[r] & 0xFFFFFFFFULL);
                }
            }
            float e[KNN];
            float ssum = 0.f;
#pragma unroll
            for (int r = 0; r < KNN; ++r) {
                e[r] = expf(dist[0] - dist[r]);
                ssum += e[r];
            }
#pragma unroll
            for (int r = 0; r < KNN; ++r) {
                wts[g * KNN + r]  = e[r] / ssum;
                nidx[g * KNN + r] = idxs[r];
            }
        }
    }
}

// ---------------------------------------------------------------------------
// kernel 2: out[b,cp,g] = sum_k w_k * mesh2[b,idx_k,cp]  (bias folded into
// mesh2 since sum_k w_k == 1). Pure gather + LDS transpose + coalesced store.
// ---------------------------------------------------------------------------
__global__ __launch_bounds__(256) void interp_gather(const float* __restrict__ mesh2,
                                                     const float* __restrict__ wts,
                                                     const int* __restrict__ nidx,
                                                     float* __restrict__ out) {
    __shared__ float lds2[64][66];  // [cp][g]
    __shared__ int   lidx[512];
    __shared__ float lwt[512];
    const int tile = blockIdx.x & 255;
    const int b    = blockIdx.x >> 8;
    const int t  = threadIdx.x;
    const int wv = __builtin_amdgcn_readfirstlane(t >> 6);
    const int ln = t & 63;
    const int g0 = tile * 64;

#pragma unroll
    for (int r = 0; r < 2; ++r) {
        int e  = r * 256 + t;
        int gc = min(g0 + (e >> 3), G_TOT - 1);
        int s  = gc * KNN + (e & 7);
        lidx[e] = nidx[s];
        lwt[e]  = wts[s];
    }
    __syncthreads();

    const float* m2b = mesh2 + (size_t)b * N_NODES * CH;
#pragma unroll 4
    for (int gi = 0; gi < 16; ++gi) {
        int gloc = wv * 16 + gi;
        float acc = 0.f;
#pragma unroll
        for (int k = 0; k < KNN; ++k) {
            int   id = lidx[gloc * KNN + k];
            float wk = lwt[gloc * KNN + k];
            acc = fmaf(wk, m2b[(size_t)id * CH + ln], acc);  // 256B/wave, ILP 8
        }
        lds2[ln][gloc] = acc;
    }
    __syncthreads();

    int g = g0 + ln;
    if (g < G_TOT) {
#pragma unroll
        for (int cs = 0; cs < 16; ++cs) {
            int cp = wv * 16 + cs;
            out[((size_t)b * CH + cp) * G_TOT + g] = lds2[cp][ln];
        }
    }
}

// ---------------------------------------------------------------------------
extern "C" void kernel_launch(void* const* d_in, const int* in_sizes, int n_in,
                              void* d_out, int out_size, void* d_ws, size_t ws_size,
                              hipStream_t stream) {
    const float* mesh = (const float*)d_in[0];  // [4][10242][64]
    const float* mv   = (const float*)d_in[1];  // [10242][3]
    const float* lat  = (const float*)d_in[2];  // [91]
    const float* lon  = (const float*)d_in[3];  // [180]
    const float* Wm   = (const float*)d_in[4];  // [64][64]
    const float* bias = (const float*)d_in[5];  // [64]
    float* out = (float*)d_out;                 // [4][64][91][180]

    float*  wts  = (float*)((char*)d_ws + WS_W_OFF);
    int*    nid  = (int*)((char*)d_ws + WS_I_OFF);
    float4* tbl  = (float4*)((char*)d_ws + WS_T_OFF);
    float*  slat = (float*)((char*)d_ws + WS_SL_OFF);
    int*    plat = (int*)((char*)d_ws + WS_PL_OFF);
    float*  slon = (float*)((char*)d_ws + WS_SO_OFF);
    int*    plon = (int*)((char*)d_ws + WS_PO_OFF);
    float*  m2   = (float*)((char*)d_ws + WS_M2_OFF);

    hipLaunchKernelGGL(prep_gemm, dim3(43 + NBATCH * 161), dim3(256), 0, stream,
                       mv, tbl, lat, lon, slat, plat, slon, plon,
                       mesh, Wm, bias, m2);
    hipLaunchKernelGGL(knn_weights, dim3(NTI * NTJ), dim3(512), 0, stream,
                       slat, plat, slon, plon, tbl, wts, nid);
    hipLaunchKernelGGL(interp_gather, dim3(NBATCH * 256), dim3(256), 0, stream,
                       m2, wts, nid, out);
}

// Round 11
// 120.428 us; speedup vs baseline: 3.5719x; 1.0274x over previous
//
#include <hip/hip_runtime.h>
#include <math.h>

#define G_TOT   16380
#define N_NODES 10242
#define LATN    91
#define LONN    180
#define CH      64
#define NBATCH  4
#define KNN     8

#define NW      8                    // waves per knn block
#define CAP     1472                 // LDS candidate capacity (expected ~300)
#define TLA     8
#define TLO     8
#define NTI     12                   // ceil(91/8)
#define NTJ     23                   // ceil(180/8)
#define KNN_BLOCKS (NTI * NTJ)       // 276
#define GEMM_TPB   81                // 128-row tiles per batch: ceil(10242/128)
#define GEMM_BLOCKS (NBATCH * GEMM_TPB)  // 324

// search radius: chord^2 = 0.0144 (r=0.12). E[nodes inside]=36.9;
// P(8th-NN beyond r) ~ 2e-9/gp; full-table fallback covers even that.
#define R2BOUND 0.0144f
#define RSNIP   0.121f               // r + slack for the patch filter

// workspace layout (bytes)
#define WS_W_OFF  0                            // float [G_TOT][8] weights
#define WS_I_OFF  (G_TOT * KNN * 4)            // int   [G_TOT][8] indices
#define WS_M2_OFF (2 * G_TOT * KNN * 4)        // float [4][N_NODES][64] mesh2

typedef unsigned long long ull;

// LDS overlays (shared via raw buffer; knn and gemm paths never coexist in a block)
struct KnnSh {
    float4 cand[CAP];            // 23552
    int    cidx[CAP];            //  5888
    ull    lists[NW][64][KNN];   // 32768
    float4 gpp[64];              //  1024
    int    gorig[64];            //   256
    float  latv[TLA]; int lati[TLA];   // this block's 8 sorted-lat values/orig idx
    float  lonv[TLO]; int loni[TLO];
    float  axv[LONN];            //   720  (axis staging for ranking)
    int    cnt; float r2tot;
};                               // ~64.3 KB
struct GemmSh {
    float amT[64][132];          // 33792  amT[c][row]  (128-row tile)
    float wtT[64][68];           // 17408  wtT[c][cp]
};                               // ~51.2 KB

// ---------------------------------------------------------------------------
// kernel 0: blocks 0..275 = spatial-patch KNN; blocks 276..599 = mesh2 gemm.
// KNN selection arithmetic is UNTOUCHED vs R10 (R8 lesson): only data
// transport changed — axis ranks computed in-block (same comparisons as the
// old prep sort), node coords read from mv directly with m2 computed via the
// byte-identical no-FMA sequence. gemm: 128-row tile, 4x4/thread, same
// c-ascending fmaf order as R10 -> bit-identical mesh2.
// ---------------------------------------------------------------------------
__global__ __launch_bounds__(512) void knn_gemm(const float* __restrict__ mv,
                                                const float* __restrict__ lat,
                                                const float* __restrict__ lon,
                                                const float* __restrict__ mesh,
                                                const float* __restrict__ Wm,
                                                const float* __restrict__ bias,
                                                float* __restrict__ mesh2,
                                                float* __restrict__ wts,
                                                int* __restrict__ nidx) {
    __shared__ __align__(16) char smem[sizeof(KnnSh)];
    const int blk = blockIdx.x, t = threadIdx.x;

    if (blk >= KNN_BLOCKS) {
        // ================= gemm path =================
        GemmSh& G = *reinterpret_cast<GemmSh*>(smem);
        const int gb   = blk - KNN_BLOCKS;
        const int b    = gb / GEMM_TPB;
        const int row0 = (gb % GEMM_TPB) * 128;
        const float* mb = mesh + (size_t)b * N_NODES * CH;

#pragma unroll
        for (int k2 = 0; k2 < 4; ++k2) {     // mesh tile: 128 rows x 16 float4
            int e = k2 * 512 + t;
            int r = e >> 4, c4 = e & 15;
            int row = row0 + r;
            float4 v = make_float4(0.f, 0.f, 0.f, 0.f);
            if (row < N_NODES) v = *(const float4*)&mb[(size_t)row * CH + c4 * 4];
            G.amT[c4 * 4 + 0][r] = v.x;
            G.amT[c4 * 4 + 1][r] = v.y;
            G.amT[c4 * 4 + 2][r] = v.z;
            G.amT[c4 * 4 + 3][r] = v.w;
        }
#pragma unroll
        for (int k2 = 0; k2 < 2; ++k2) {     // W: 64 rows x 16 float4
            int e = k2 * 512 + t;
            int r = e >> 4, c4 = e & 15;     // r == cp
            float4 wv = *(const float4*)&Wm[r * CH + c4 * 4];
            G.wtT[c4 * 4 + 0][r] = wv.x;
            G.wtT[c4 * 4 + 1][r] = wv.y;
            G.wtT[c4 * 4 + 2][r] = wv.z;
            G.wtT[c4 * 4 + 3][r] = wv.w;
        }
        __syncthreads();

        const int tr = t & 31, tc = t >> 5;
        const int r0 = tr * 4, cp0 = tc * 4;
        float acc[4][4];
#pragma unroll
        for (int i = 0; i < 4; ++i)
#pragma unroll
            for (int j = 0; j < 4; ++j) acc[i][j] = 0.f;

        for (int c = 0; c < 64; ++c) {
            float4 av = *(const float4*)&G.amT[c][r0];
            float4 wv = *(const float4*)&G.wtT[c][cp0];
            float a4[4] = {av.x, av.y, av.z, av.w};
            float w4[4] = {wv.x, wv.y, wv.z, wv.w};
#pragma unroll
            for (int i = 0; i < 4; ++i)
#pragma unroll
                for (int j = 0; j < 4; ++j)
                    acc[i][j] = fmaf(a4[i], w4[j], acc[i][j]);
        }

        float4 bv = *(const float4*)&bias[cp0];
#pragma unroll
        for (int i = 0; i < 4; ++i) {
            int row = row0 + r0 + i;
            if (row < N_NODES) {
                float4 o = make_float4(acc[i][0] + bv.x, acc[i][1] + bv.y,
                                       acc[i][2] + bv.z, acc[i][3] + bv.w);
                *(float4*)&mesh2[((size_t)b * N_NODES + row) * CH + cp0] = o;
            }
        }
        return;
    }

    // ================= knn path =================
    KnnSh& K = *reinterpret_cast<KnnSh*>(smem);
    const int gl = t & 63;
    const int w  = __builtin_amdgcn_readfirstlane(t >> 6);
    const int ti = blk / NTJ, tj = blk % NTJ;

    // ---- axis ranking (same comparisons as the old global sort) ----
    if (t < LATN) K.axv[t] = lat[t];
    __syncthreads();
    if (t < LATN) {
        float v = K.axv[t];
        int r = 0;
        for (int j = 0; j < LATN; ++j) {
            float o = K.axv[j];
            r += (o < v) || (o == v && j < t);
        }
        int rr = r - ti * TLA;
        if (rr >= 0 && rr < TLA) { K.latv[rr] = v; K.lati[rr] = t; }
    }
    __syncthreads();
    if (t < LONN) K.axv[t] = lon[t];
    __syncthreads();
    if (t < LONN) {
        float v = K.axv[t];
        int r = 0;
        for (int j = 0; j < LONN; ++j) {
            float o = K.axv[j];
            r += (o < v) || (o == v && j < t);
        }
        int rr = r - tj * TLO;
        if (rr >= 0 && rr < TLO) { K.lonv[rr] = v; K.loni[rr] = t; }
    }
    __syncthreads();

    // ---- phase 0: gp coords (np-f32 exact), mapping ----
    if (t < 64) {
        if (t == 0) K.cnt = 0;
        int ar = ti * TLA + (t >> 3), orr = tj * TLO + (t & 7);
        bool val = (ar < LATN) && (orr < LONN);
        int a = min(ar, LATN - 1) - ti * TLA;   // clamped rank stays in window
        int o = min(orr, LONN - 1) - tj * TLO;
        double dla = (double)K.latv[a], dlo = (double)K.lonv[o];
        float cl = (float)cos(dla), sl = (float)sin(dla);
        float co = (float)cos(dlo), so = (float)sin(dlo);
        float gx = __fmul_rn(cl, co), gy = __fmul_rn(cl, so), gz = sl;
        float g2 = __fadd_rn(__fadd_rn(__fmul_rn(gx, gx), __fmul_rn(gy, gy)),
                             __fmul_rn(gz, gz));
        K.gpp[t]   = make_float4(gx, gy, gz, g2);
        K.gorig[t] = val ? (K.lati[a] * LONN + K.loni[o]) : -1;
    }
    __syncthreads();
    if (t < 64) {
        float4 c = K.gpp[27];
        float4 g = K.gpp[t];
        float dx = g.x - c.x, dy = g.y - c.y, dz = g.z - c.z;
        float d2c = dx * dx + dy * dy + dz * dz;
#pragma unroll
        for (int off = 32; off > 0; off >>= 1)
            d2c = fmaxf(d2c, __shfl_xor(d2c, off));
        if (t == 0) {
            float R = sqrtf(d2c) + RSNIP;
            K.r2tot = R * R + 1e-3f;
        }
    }
    __syncthreads();

    // ---- phase A: compaction from mv, loads staged 4-deep ----
    {
        float4 c = K.gpp[27];
        float r2t = K.r2tot;
        for (int j0 = t; j0 < N_NODES; j0 += 512 * 4) {
            float nx[4], ny[4], nz[4];
#pragma unroll
            for (int u = 0; u < 4; ++u) {
                int j = j0 + u * 512;
                int jj = (j < N_NODES) ? j : 0;
                nx[u] = mv[3 * jj + 0];
                ny[u] = mv[3 * jj + 1];
                nz[u] = mv[3 * jj + 2];
            }
#pragma unroll
            for (int u = 0; u < 4; ++u) {
                int j = j0 + u * 512;
                float dx = nx[u] - c.x, dy = ny[u] - c.y, dz = nz[u] - c.z;
                float d2c = dx * dx + dy * dy + dz * dz;
                if (d2c <= r2t && j < N_NODES) {
                    int pos = atomicAdd(&K.cnt, 1);
                    if (pos < CAP) {
                        // m2: byte-identical no-FMA sequence (np f32)
                        float m2 = __fadd_rn(__fadd_rn(__fmul_rn(nx[u], nx[u]),
                                                       __fmul_rn(ny[u], ny[u])),
                                             __fmul_rn(nz[u], nz[u]));
                        K.cand[pos] = make_float4(nx[u], ny[u], nz[u], m2);
                        K.cidx[pos] = j;
                    }
                }
            }
        }
    }
    __syncthreads();
    const int  ncand = K.cnt;
    const bool ovf   = ncand > CAP;

    // ---- phase B: per-lane top-8 (byte-for-byte R7/R10 logic) ----
    const float4 gme = K.gpp[gl];
    const float  gx = gme.x, gy = gme.y, gz = gme.z, g2 = gme.w;
    const float  ax = 2.0f * gx, ay = 2.0f * gy, az = 2.0f * gz;

    ull kk[KNN];
#pragma unroll
    for (int q = 0; q < KNN; ++q) kk[q] = ~0ull;

    if (!ovf) {
        const int nn = ncand;
        for (int ci = w; ci < nn; ci += NW) {
            float4 nd = K.cand[ci];
            int    j  = K.cidx[ci];
            float dot2 = __fmaf_rn(az, nd.z,
                          __fmaf_rn(ay, nd.y, __fmul_rn(ax, nd.x)));
            float d2 = __fsub_rn(__fadd_rn(g2, nd.w), dot2);
            if (d2 <= R2BOUND) {
                float sq = sqrtf(fmaxf(d2, 1e-12f));
                ull key = ((ull)__float_as_uint(sq) << 32) | (ull)(unsigned)j;
                if (key < kk[KNN - 1]) {
                    kk[KNN - 1] = key;
#pragma unroll
                    for (int q = KNN - 1; q > 0; --q) {
                        ull a = kk[q - 1], c = kk[q];
                        bool m = c < a;
                        kk[q - 1] = m ? c : a;
                        kk[q]     = m ? a : c;
                    }
                }
            }
        }
    } else {
        // cand overflow fallback (never expected): full mv scan, same key math
        for (int j = w * 1281; j < (w + 1) * 1281 && j < N_NODES; ++j) {
            float x = mv[3 * j], y = mv[3 * j + 1], z = mv[3 * j + 2];
            float m2 = __fadd_rn(__fadd_rn(__fmul_rn(x, x), __fmul_rn(y, y)),
                                 __fmul_rn(z, z));
            float dot2 = __fmaf_rn(az, z, __fmaf_rn(ay, y, __fmul_rn(ax, x)));
            float d2 = __fsub_rn(__fadd_rn(g2, m2), dot2);
            if (d2 <= R2BOUND) {
                float sq = sqrtf(fmaxf(d2, 1e-12f));
                ull key = ((ull)__float_as_uint(sq) << 32) | (ull)(unsigned)j;
                if (key < kk[KNN - 1]) {
                    kk[KNN - 1] = key;
#pragma unroll
                    for (int q = KNN - 1; q > 0; --q) {
                        ull a = kk[q - 1], c = kk[q];
                        bool m = c < a;
                        kk[q - 1] = m ? c : a;
                        kk[q]     = m ? a : c;
                    }
                }
            }
        }
    }

#pragma unroll
    for (int q = 0; q < KNN; ++q) K.lists[w][gl][q] = kk[q];
    __syncthreads();

    // ---- merge + softmax + scatter (byte-for-byte R7/R10) ----
    if (t < 64) {
        int g = K.gorig[t];
        if (g >= 0) {
            int pos[NW];
#pragma unroll
            for (int s = 0; s < NW; ++s) pos[s] = 0;
            float dist[KNN];
            int   idxs[KNN];
            bool  bad = false;
            for (int r = 0; r < KNN; ++r) {
                ull best = ~0ull;
                int bs = 0;
#pragma unroll
                for (int s = 0; s < NW; ++s) {
                    ull v = (pos[s] < KNN) ? K.lists[s][t][pos[s]] : ~0ull;
                    if (v < best) { best = v; bs = s; }
                }
                if (best == ~0ull) bad = true;
                dist[r] = __uint_as_float((unsigned)(best >> 32));
                idxs[r] = (int)(best & 0xFFFFFFFFULL);
#pragma unroll
                for (int s = 0; s < NW; ++s) pos[s] += (s == bs) ? 1 : 0;
            }
            if (bad) {
                // <8 in radius (P~2e-9/gp): per-gp brute force over mv
                float4 gm = K.gpp[t];
                float bx = 2.0f * gm.x, by = 2.0f * gm.y, bz = 2.0f * gm.z;
                ull mm[KNN];
#pragma unroll
                for (int q = 0; q < KNN; ++q) mm[q] = ~0ull;
                for (int j = 0; j < N_NODES; ++j) {
                    float x = mv[3 * j], y = mv[3 * j + 1], z = mv[3 * j + 2];
                    float m2 = __fadd_rn(__fadd_rn(__fmul_rn(x, x), __fmul_rn(y, y)),
                                         __fmul_rn(z, z));
                    float dot2 = __fmaf_rn(bz, z, __fmaf_rn(by, y, __fmul_rn(bx, x)));
                    float d2 = __fsub_rn(__fadd_rn(gm.w, m2), dot2);
                    float sq = sqrtf(fmaxf(d2, 1e-12f));
                    ull key = ((ull)__float_as_uint(sq) << 32) | (ull)(unsigned)j;
                    if (key < mm[KNN - 1]) {
                        mm[KNN - 1] = key;
#pragma unroll
                        for (int q = KNN - 1; q > 0; --q) {
                            ull a = mm[q - 1], c = mm[q];
                            bool m = c < a;
                            mm[q - 1] = m ? c : a;
                            mm[q]     = m ? a : c;
                        }
                    }
                }
#pragma unroll
                for (int r = 0; r < KNN; ++r) {
                    dist[r] = __uint_as_float((unsigned)(mm[r] >> 32));
                    idxs[r] = (int)(mm[r] & 0xFFFFFFFFULL);
                }
            }
            float e[KNN];
            float ssum = 0.f;
#pragma unroll
            for (int r = 0; r < KNN; ++r) {
                e[r] = expf(dist[0] - dist[r]);
                ssum += e[r];
            }
#pragma unroll
            for (int r = 0; r < KNN; ++r) {
                wts[g * KNN + r]  = e[r] / ssum;
                nidx[g * KNN + r] = idxs[r];
            }
        }
    }
}

// ---------------------------------------------------------------------------
// kernel 1: out[b,cp,g] = sum_k w_k * mesh2[b,idx_k,cp]  (bias folded into
// mesh2 since sum_k w_k == 1). Byte-identical to R10's interp_gather.
// ---------------------------------------------------------------------------
__global__ __launch_bounds__(256) void interp_gather(const float* __restrict__ mesh2,
                                                     const float* __restrict__ wts,
                                                     const int* __restrict__ nidx,
                                                     float* __restrict__ out) {
    __shared__ float lds2[64][66];  // [cp][g]
    __shared__ int   lidx[512];
    __shared__ float lwt[512];
    const int tile = blockIdx.x & 255;
    const int b    = blockIdx.x >> 8;
    const int t  = threadIdx.x;
    const int wv = __builtin_amdgcn_readfirstlane(t >> 6);
    const int ln = t & 63;
    const int g0 = tile * 64;

#pragma unroll
    for (int r = 0; r < 2; ++r) {
        int e  = r * 256 + t;
        int gc = min(g0 + (e >> 3), G_TOT - 1);
        int s  = gc * KNN + (e & 7);
        lidx[e] = nidx[s];
        lwt[e]  = wts[s];
    }
    __syncthreads();

    const float* m2b = mesh2 + (size_t)b * N_NODES * CH;
#pragma unroll 4
    for (int gi = 0; gi < 16; ++gi) {
        int gloc = wv * 16 + gi;
        float acc = 0.f;
#pragma unroll
        for (int k = 0; k < KNN; ++k) {
            int   id = lidx[gloc * KNN + k];
            float wk = lwt[gloc * KNN + k];
            acc = fmaf(wk, m2b[(size_t)id * CH + ln], acc);  // 256B/wave, ILP 8
        }
        lds2[ln][gloc] = acc;
    }
    __syncthreads();

    int g = g0 + ln;
    if (g < G_TOT) {
#pragma unroll
        for (int cs = 0; cs < 16; ++cs) {
            int cp = wv * 16 + cs;
            out[((size_t)b * CH + cp) * G_TOT + g] = lds2[cp][ln];
        }
    }
}

// ---------------------------------------------------------------------------
extern "C" void kernel_launch(void* const* d_in, const int* in_sizes, int n_in,
                              void* d_out, int out_size, void* d_ws, size_t ws_size,
                              hipStream_t stream) {
    const float* mesh = (const float*)d_in[0];  // [4][10242][64]
    const float* mv   = (const float*)d_in[1];  // [10242][3]
    const float* lat  = (const float*)d_in[2];  // [91]
    const float* lon  = (const float*)d_in[3];  // [180]
    const float* Wm   = (const float*)d_in[4];  // [64][64]
    const float* bias = (const float*)d_in[5];  // [64]
    float* out = (float*)d_out;                 // [4][64][91][180]

    float* wts = (float*)((char*)d_ws + WS_W_OFF);
    int*   nid = (int*)((char*)d_ws + WS_I_OFF);
    float* m2  = (float*)((char*)d_ws + WS_M2_OFF);

    hipLaunchKernelGGL(knn_gemm, dim3(KNN_BLOCKS + GEMM_BLOCKS), dim3(512), 0, stream,
                       mv, lat, lon, mesh, Wm, bias, m2, wts, nid);
    hipLaunchKernelGGL(interp_gather, dim3(NBATCH * 256), dim3(256), 0, stream,
                       m2, wts, nid, out);
}

// Round 12
// 117.014 us; speedup vs baseline: 3.6761x; 1.0292x over previous
//
#include <hip/hip_runtime.h>
#include <math.h>

#define G_TOT   16380
#define N_NODES 10242
#define LATN    91
#define LONN    180
#define CH      64
#define NBATCH  4
#define KNN     8

#define NW      8                    // waves per knn block
#define CAP     1472                 // LDS candidate capacity (expected ~300)
#define TLA     8
#define TLO     8
#define NTI     12                   // ceil(91/8)
#define NTJ     23                   // ceil(180/8)
#define KNN_BLOCKS (NTI * NTJ)       // 276
#define GEMM_TPB   81                // 128-row tiles per batch: ceil(10242/128)
#define GEMM_BLOCKS (NBATCH * GEMM_TPB)  // 324

// search radius: chord^2 = 0.0144 (r=0.12). E[nodes inside]=36.9;
// P(8th-NN beyond r) ~ 2e-9/gp; full-table fallback covers even that.
#define R2BOUND 0.0144f
#define RSNIP   0.121f               // r + slack for the patch filter

// workspace layout (bytes)
#define WS_W_OFF  0                            // float [G_TOT][8] weights
#define WS_I_OFF  (G_TOT * KNN * 4)            // int   [G_TOT][8] indices
#define WS_M2_OFF (2 * G_TOT * KNN * 4)        // float [4][N_NODES][64] mesh2

typedef unsigned long long ull;

// LDS overlays (shared via raw buffer; knn and gemm paths never coexist in a block)
struct KnnSh {
    float4 cand[CAP];            // 23552
    int    cidx[CAP];            //  5888
    ull    lists[NW][64][KNN];   // 32768
    float4 gpp[64];              //  1024
    int    gorig[64];            //   256
    float  latv[TLA]; int lati[TLA];
    float  lonv[TLO]; int loni[TLO];
    float  axla[LATN];           //   364  lat staging
    float  axlo[LONN];           //   720  lon staging
    int    cnt; float r2tot;
};                               // ~64.7 KB (< 64 KiB static limit)
struct GemmSh {
    float amT[64][132];          // 33792  amT[c][row]  (128-row tile)
    float wtT[64][68];           // 17408  wtT[c][cp]
};                               // ~51.2 KB

// ---------------------------------------------------------------------------
// kernel 0: blocks 0..275 = spatial-patch KNN; blocks 276..599 = mesh2 gemm.
// R12 change vs R11 (ONLY): axis ranking reads staged 8-deep into independent
// registers (R11's serial dependent ds_read chain: up to 271 x ~120cyc
// latency ~ 13us/block — the prime suspect for the unexplained block time),
// and lat/lon ranked concurrently on different waves. Same values, same
// comparisons, same ranks -> bit-identical downstream. Selection arithmetic
// byte-for-byte R11 (R8 lesson).
// ---------------------------------------------------------------------------
__global__ __launch_bounds__(512) void knn_gemm(const float* __restrict__ mv,
                                                const float* __restrict__ lat,
                                                const float* __restrict__ lon,
                                                const float* __restrict__ mesh,
                                                const float* __restrict__ Wm,
                                                const float* __restrict__ bias,
                                                float* __restrict__ mesh2,
                                                float* __restrict__ wts,
                                                int* __restrict__ nidx) {
    __shared__ __align__(16) char smem[sizeof(KnnSh)];
    const int blk = blockIdx.x, t = threadIdx.x;

    if (blk >= KNN_BLOCKS) {
        // ================= gemm path =================
        GemmSh& G = *reinterpret_cast<GemmSh*>(smem);
        const int gb   = blk - KNN_BLOCKS;
        const int b    = gb / GEMM_TPB;
        const int row0 = (gb % GEMM_TPB) * 128;
        const float* mb = mesh + (size_t)b * N_NODES * CH;

#pragma unroll
        for (int k2 = 0; k2 < 4; ++k2) {     // mesh tile: 128 rows x 16 float4
            int e = k2 * 512 + t;
            int r = e >> 4, c4 = e & 15;
            int row = row0 + r;
            float4 v = make_float4(0.f, 0.f, 0.f, 0.f);
            if (row < N_NODES) v = *(const float4*)&mb[(size_t)row * CH + c4 * 4];
            G.amT[c4 * 4 + 0][r] = v.x;
            G.amT[c4 * 4 + 1][r] = v.y;
            G.amT[c4 * 4 + 2][r] = v.z;
            G.amT[c4 * 4 + 3][r] = v.w;
        }
#pragma unroll
        for (int k2 = 0; k2 < 2; ++k2) {     // W: 64 rows x 16 float4
            int e = k2 * 512 + t;
            int r = e >> 4, c4 = e & 15;     // r == cp
            float4 wv = *(const float4*)&Wm[r * CH + c4 * 4];
            G.wtT[c4 * 4 + 0][r] = wv.x;
            G.wtT[c4 * 4 + 1][r] = wv.y;
            G.wtT[c4 * 4 + 2][r] = wv.z;
            G.wtT[c4 * 4 + 3][r] = wv.w;
        }
        __syncthreads();

        const int tr = t & 31, tc = t >> 5;
        const int r0 = tr * 4, cp0 = tc * 4;
        float acc[4][4];
#pragma unroll
        for (int i = 0; i < 4; ++i)
#pragma unroll
            for (int j = 0; j < 4; ++j) acc[i][j] = 0.f;

        for (int c = 0; c < 64; ++c) {
            float4 av = *(const float4*)&G.amT[c][r0];
            float4 wv = *(const float4*)&G.wtT[c][cp0];
            float a4[4] = {av.x, av.y, av.z, av.w};
            float w4[4] = {wv.x, wv.y, wv.z, wv.w};
#pragma unroll
            for (int i = 0; i < 4; ++i)
#pragma unroll
                for (int j = 0; j < 4; ++j)
                    acc[i][j] = fmaf(a4[i], w4[j], acc[i][j]);
        }

        float4 bv = *(const float4*)&bias[cp0];
#pragma unroll
        for (int i = 0; i < 4; ++i) {
            int row = row0 + r0 + i;
            if (row < N_NODES) {
                float4 o = make_float4(acc[i][0] + bv.x, acc[i][1] + bv.y,
                                       acc[i][2] + bv.z, acc[i][3] + bv.w);
                *(float4*)&mesh2[((size_t)b * N_NODES + row) * CH + cp0] = o;
            }
        }
        return;
    }

    // ================= knn path =================
    KnnSh& K = *reinterpret_cast<KnnSh*>(smem);
    const int gl = t & 63;
    const int w  = __builtin_amdgcn_readfirstlane(t >> 6);
    const int ti = blk / NTJ, tj = blk % NTJ;

    // ---- axis staging: lat on waves 0-1, lon on waves 4-6 (concurrent) ----
    if (t < LATN) K.axla[t] = lat[t];
    if (t >= 256 && t < 256 + LONN) K.axlo[t - 256] = lon[t - 256];
    __syncthreads();

    // ---- ranking: reads staged 8-deep (independent -> latency overlapped);
    //      same comparisons as R11 -> identical ranks ----
    if (t < LATN) {
        float v = K.axla[t];
        int r = 0;
        int j0 = 0;
        for (; j0 + 8 <= LATN; j0 += 8) {
            float o[8];
#pragma unroll
            for (int u = 0; u < 8; ++u) o[u] = K.axla[j0 + u];
#pragma unroll
            for (int u = 0; u < 8; ++u)
                r += (o[u] < v) || (o[u] == v && (j0 + u) < t);
        }
        for (; j0 < LATN; ++j0) {
            float o = K.axla[j0];
            r += (o < v) || (o == v && j0 < t);
        }
        int rr = r - ti * TLA;
        if (rr >= 0 && rr < TLA) { K.latv[rr] = v; K.lati[rr] = t; }
    }
    if (t >= 256 && t < 256 + LONN) {
        int tt = t - 256;
        float v = K.axlo[tt];
        int r = 0;
        int j0 = 0;
        for (; j0 + 8 <= LONN; j0 += 8) {
            float o[8];
#pragma unroll
            for (int u = 0; u < 8; ++u) o[u] = K.axlo[j0 + u];
#pragma unroll
            for (int u = 0; u < 8; ++u)
                r += (o[u] < v) || (o[u] == v && (j0 + u) < tt);
        }
        for (; j0 < LONN; ++j0) {
            float o = K.axlo[j0];
            r += (o < v) || (o == v && j0 < tt);
        }
        int rr = r - tj * TLO;
        if (rr >= 0 && rr < TLO) { K.lonv[rr] = v; K.loni[rr] = tt; }
    }
    __syncthreads();

    // ---- phase 0: gp coords (np-f32 exact), mapping ----
    if (t < 64) {
        if (t == 0) K.cnt = 0;
        int ar = ti * TLA + (t >> 3), orr = tj * TLO + (t & 7);
        bool val = (ar < LATN) && (orr < LONN);
        int a = min(ar, LATN - 1) - ti * TLA;   // clamped rank stays in window
        int o = min(orr, LONN - 1) - tj * TLO;
        double dla = (double)K.latv[a], dlo = (double)K.lonv[o];
        float cl = (float)cos(dla), sl = (float)sin(dla);
        float co = (float)cos(dlo), so = (float)sin(dlo);
        float gx = __fmul_rn(cl, co), gy = __fmul_rn(cl, so), gz = sl;
        float g2 = __fadd_rn(__fadd_rn(__fmul_rn(gx, gx), __fmul_rn(gy, gy)),
                             __fmul_rn(gz, gz));
        K.gpp[t]   = make_float4(gx, gy, gz, g2);
        K.gorig[t] = val ? (K.lati[a] * LONN + K.loni[o]) : -1;
    }
    __syncthreads();
    if (t < 64) {
        float4 c = K.gpp[27];
        float4 g = K.gpp[t];
        float dx = g.x - c.x, dy = g.y - c.y, dz = g.z - c.z;
        float d2c = dx * dx + dy * dy + dz * dz;
#pragma unroll
        for (int off = 32; off > 0; off >>= 1)
            d2c = fmaxf(d2c, __shfl_xor(d2c, off));
        if (t == 0) {
            float R = sqrtf(d2c) + RSNIP;
            K.r2tot = R * R + 1e-3f;
        }
    }
    __syncthreads();

    // ---- phase A: compaction from mv, loads staged 4-deep ----
    {
        float4 c = K.gpp[27];
        float r2t = K.r2tot;
        for (int j0 = t; j0 < N_NODES; j0 += 512 * 4) {
            float nx[4], ny[4], nz[4];
#pragma unroll
            for (int u = 0; u < 4; ++u) {
                int j = j0 + u * 512;
                int jj = (j < N_NODES) ? j : 0;
                nx[u] = mv[3 * jj + 0];
                ny[u] = mv[3 * jj + 1];
                nz[u] = mv[3 * jj + 2];
            }
#pragma unroll
            for (int u = 0; u < 4; ++u) {
                int j = j0 + u * 512;
                float dx = nx[u] - c.x, dy = ny[u] - c.y, dz = nz[u] - c.z;
                float d2c = dx * dx + dy * dy + dz * dz;
                if (d2c <= r2t && j < N_NODES) {
                    int pos = atomicAdd(&K.cnt, 1);
                    if (pos < CAP) {
                        // m2: byte-identical no-FMA sequence (np f32)
                        float m2 = __fadd_rn(__fadd_rn(__fmul_rn(nx[u], nx[u]),
                                                       __fmul_rn(ny[u], ny[u])),
                                             __fmul_rn(nz[u], nz[u]));
                        K.cand[pos] = make_float4(nx[u], ny[u], nz[u], m2);
                        K.cidx[pos] = j;
                    }
                }
            }
        }
    }
    __syncthreads();
    const int  ncand = K.cnt;
    const bool ovf   = ncand > CAP;

    // ---- phase B: per-lane top-8 (byte-for-byte R7/R10/R11 logic) ----
    const float4 gme = K.gpp[gl];
    const float  gx = gme.x, gy = gme.y, gz = gme.z, g2 = gme.w;
    const float  ax = 2.0f * gx, ay = 2.0f * gy, az = 2.0f * gz;

    ull kk[KNN];
#pragma unroll
    for (int q = 0; q < KNN; ++q) kk[q] = ~0ull;

    if (!ovf) {
        const int nn = ncand;
        for (int ci = w; ci < nn; ci += NW) {
            float4 nd = K.cand[ci];
            int    j  = K.cidx[ci];
            float dot2 = __fmaf_rn(az, nd.z,
                          __fmaf_rn(ay, nd.y, __fmul_rn(ax, nd.x)));
            float d2 = __fsub_rn(__fadd_rn(g2, nd.w), dot2);
            if (d2 <= R2BOUND) {
                float sq = sqrtf(fmaxf(d2, 1e-12f));
                ull key = ((ull)__float_as_uint(sq) << 32) | (ull)(unsigned)j;
                if (key < kk[KNN - 1]) {
                    kk[KNN - 1] = key;
#pragma unroll
                    for (int q = KNN - 1; q > 0; --q) {
                        ull a = kk[q - 1], c = kk[q];
                        bool m = c < a;
                        kk[q - 1] = m ? c : a;
                        kk[q]     = m ? a : c;
                    }
                }
            }
        }
    } else {
        // cand overflow fallback (never expected): full mv scan, same key math
        for (int j = w * 1281; j < (w + 1) * 1281 && j < N_NODES; ++j) {
            float x = mv[3 * j], y = mv[3 * j + 1], z = mv[3 * j + 2];
            float m2 = __fadd_rn(__fadd_rn(__fmul_rn(x, x), __fmul_rn(y, y)),
                                 __fmul_rn(z, z));
            float dot2 = __fmaf_rn(az, z, __fmaf_rn(ay, y, __fmul_rn(ax, x)));
            float d2 = __fsub_rn(__fadd_rn(g2, m2), dot2);
            if (d2 <= R2BOUND) {
                float sq = sqrtf(fmaxf(d2, 1e-12f));
                ull key = ((ull)__float_as_uint(sq) << 32) | (ull)(unsigned)j;
                if (key < kk[KNN - 1]) {
                    kk[KNN - 1] = key;
#pragma unroll
                    for (int q = KNN - 1; q > 0; --q) {
                        ull a = kk[q - 1], c = kk[q];
                        bool m = c < a;
                        kk[q - 1] = m ? c : a;
                        kk[q]     = m ? a : c;
                    }
                }
            }
        }
    }

#pragma unroll
    for (int q = 0; q < KNN; ++q) K.lists[w][gl][q] = kk[q];
    __syncthreads();

    // ---- merge + softmax + scatter (byte-for-byte R7/R10/R11) ----
    if (t < 64) {
        int g = K.gorig[t];
        if (g >= 0) {
            int pos[NW];
#pragma unroll
            for (int s = 0; s < NW; ++s) pos[s] = 0;
            float dist[KNN];
            int   idxs[KNN];
            bool  bad = false;
            for (int r = 0; r < KNN; ++r) {
                ull best = ~0ull;
                int bs = 0;
#pragma unroll
                for (int s = 0; s < NW; ++s) {
                    ull v = (pos[s] < KNN) ? K.lists[s][t][pos[s]] : ~0ull;
                    if (v < best) { best = v; bs = s; }
                }
                if (best == ~0ull) bad = true;
                dist[r] = __uint_as_float((unsigned)(best >> 32));
                idxs[r] = (int)(best & 0xFFFFFFFFULL);
#pragma unroll
                for (int s = 0; s < NW; ++s) pos[s] += (s == bs) ? 1 : 0;
            }
            if (bad) {
                // <8 in radius (P~2e-9/gp): per-gp brute force over mv
                float4 gm = K.gpp[t];
                float bx = 2.0f * gm.x, by = 2.0f * gm.y, bz = 2.0f * gm.z;
                ull mm[KNN];
#pragma unroll
                for (int q = 0; q < KNN; ++q) mm[q] = ~0ull;
                for (int j = 0; j < N_NODES; ++j) {
                    float x = mv[3 * j], y = mv[3 * j + 1], z = mv[3 * j + 2];
                    float m2 = __fadd_rn(__fadd_rn(__fmul_rn(x, x), __fmul_rn(y, y)),
                                         __fmul_rn(z, z));
                    float dot2 = __fmaf_rn(bz, z, __fmaf_rn(by, y, __fmul_rn(bx, x)));
                    float d2 = __fsub_rn(__fadd_rn(gm.w, m2), dot2);
                    float sq = sqrtf(fmaxf(d2, 1e-12f));
                    ull key = ((ull)__float_as_uint(sq) << 32) | (ull)(unsigned)j;
                    if (key < mm[KNN - 1]) {
                        mm[KNN - 1] = key;
#pragma unroll
                        for (int q = KNN - 1; q > 0; --q) {
                            ull a = mm[q - 1], c = mm[q];
                            bool m = c < a;
                            mm[q - 1] = m ? c : a;
                            mm[q]     = m ? a : c;
                        }
                    }
                }
#pragma unroll
                for (int r = 0; r < KNN; ++r) {
                    dist[r] = __uint_as_float((unsigned)(mm[r] >> 32));
                    idxs[r] = (int)(mm[r] & 0xFFFFFFFFULL);
                }
            }
            float e[KNN];
            float ssum = 0.f;
#pragma unroll
            for (int r = 0; r < KNN; ++r) {
                e[r] = expf(dist[0] - dist[r]);
                ssum += e[r];
            }
#pragma unroll
            for (int r = 0; r < KNN; ++r) {
                wts[g * KNN + r]  = e[r] / ssum;
                nidx[g * KNN + r] = idxs[r];
            }
        }
    }
}

// ---------------------------------------------------------------------------
// kernel 1: out[b,cp,g] = sum_k w_k * mesh2[b,idx_k,cp]  (bias folded into
// mesh2 since sum_k w_k == 1). Byte-identical to R10/R11 interp_gather.
// ---------------------------------------------------------------------------
__global__ __launch_bounds__(256) void interp_gather(const float* __restrict__ mesh2,
                                                     const float* __restrict__ wts,
                                                     const int* __restrict__ nidx,
                                                     float* __restrict__ out) {
    __shared__ float lds2[64][66];  // [cp][g]
    __shared__ int   lidx[512];
    __shared__ float lwt[512];
    const int tile = blockIdx.x & 255;
    const int b    = blockIdx.x >> 8;
    const int t  = threadIdx.x;
    const int wv = __builtin_amdgcn_readfirstlane(t >> 6);
    const int ln = t & 63;
    const int g0 = tile * 64;

#pragma unroll
    for (int r = 0; r < 2; ++r) {
        int e  = r * 256 + t;
        int gc = min(g0 + (e >> 3), G_TOT - 1);
        int s  = gc * KNN + (e & 7);
        lidx[e] = nidx[s];
        lwt[e]  = wts[s];
    }
    __syncthreads();

    const float* m2b = mesh2 + (size_t)b * N_NODES * CH;
#pragma unroll 4
    for (int gi = 0; gi < 16; ++gi) {
        int gloc = wv * 16 + gi;
        float acc = 0.f;
#pragma unroll
        for (int k = 0; k < KNN; ++k) {
            int   id = lidx[gloc * KNN + k];
            float wk = lwt[gloc * KNN + k];
            acc = fmaf(wk, m2b[(size_t)id * CH + ln], acc);  // 256B/wave, ILP 8
        }
        lds2[ln][gloc] = acc;
    }
    __syncthreads();

    int g = g0 + ln;
    if (g < G_TOT) {
#pragma unroll
        for (int cs = 0; cs < 16; ++cs) {
            int cp = wv * 16 + cs;
            out[((size_t)b * CH + cp) * G_TOT + g] = lds2[cp][ln];
        }
    }
}

// ---------------------------------------------------------------------------
extern "C" void kernel_launch(void* const* d_in, const int* in_sizes, int n_in,
                              void* d_out, int out_size, void* d_ws, size_t ws_size,
                              hipStream_t stream) {
    const float* mesh = (const float*)d_in[0];  // [4][10242][64]
    const float* mv   = (const float*)d_in[1];  // [10242][3]
    const float* lat  = (const float*)d_in[2];  // [91]
    const float* lon  = (const float*)d_in[3];  // [180]
    const float* Wm   = (const float*)d_in[4];  // [64][64]
    const float* bias = (const float*)d_in[5];  // [64]
    float* out = (float*)d_out;                 // [4][64][91][180]

    float* wts = (float*)((char*)d_ws + WS_W_OFF);
    int*   nid = (int*)((char*)d_ws + WS_I_OFF);
    float* m2  = (float*)((char*)d_ws + WS_M2_OFF);

    hipLaunchKernelGGL(knn_gemm, dim3(KNN_BLOCKS + GEMM_BLOCKS), dim3(512), 0, stream,
                       mv, lat, lon, mesh, Wm, bias, m2, wts, nid);
    hipLaunchKernelGGL(interp_gather, dim3(NBATCH * 256), dim3(256), 0, stream,
                       m2, wts, nid, out);
}